// Round 5
// baseline (493.545 us; speedup 1.0000x reference)
//
#include <hip/hip_runtime.h>

// VectorQuantizer on MI355X — np-fp32-exact (verified R4: absmax 0.0), argmin
// GEMM moved to bf16-split MFMA with a tau-guarded exact-rescan for close rows.
//
// np ref (verified bit-exact in R4):
//   xx[n] = pairwise fp32 sum of x*x (products pre-rounded)
//   ee[k] = same over emb
//   dot   = d-sequential fp32 fma chain (sgemm)
//   s     = fl( fl(xx+ee) - 2*dot ), argmin = first minimum.
// MFMA approx: x = xh+xl, e = eh+el (bf16 RNE splits); dot' = xh*eh+xh*el+xl*eh
// accumulated fp32 by v_mfma_f32_16x16x32_bf16. |2(dot'-dot_chain)| <~ 1e-6;
// s-grid ulp <= 3.05e-5 -> if approx top-2 gap > TAU=1e-4 the MFMA winner is
// provably the np argmin; else the row is re-scored with the exact np formula
// over all 1024 codes (expected ~1.4% of rows).
//
// ws (float units):
//   0 sumsq | 1 nflag | 64 counts[1024] | 1088 ee[1024] | 2112 xx[32768]
//   34880 partv1[8*32768] | 297024 partv2[8*32768] | 559168 parti[8*32768]
//   821312 worklist[8192] | 829504 EhW ushort[262144] | 960576 ElW ushort[262144]
//   -> ~4.4 MB total.

#define NROWS 32768
#define FLAG_CAP 8192
#define GAP_TAU 1e-4f

typedef __attribute__((ext_vector_type(8))) short short8;
typedef __attribute__((ext_vector_type(8))) unsigned short ushort8;
typedef __attribute__((ext_vector_type(4))) float f32x4;

__device__ __forceinline__ unsigned short bf16_rne(float v) {
    unsigned int u = __float_as_uint(v);
    return (unsigned short)((u + 0x7fffu + ((u >> 16) & 1u)) >> 16);
}
__device__ __forceinline__ float bf16_to_f(unsigned short h) {
    return __uint_as_float(((unsigned int)h) << 16);
}

// numpy pairwise sum of squares over 256: pw128+pw128, 8-lane accumulators.
template <int STRIDE>
__device__ __forceinline__ float np_sumsq256(const float* __restrict__ p) {
    float half[2];
#pragma unroll
    for (int h = 0; h < 2; ++h) {
        float r[8];
#pragma unroll
        for (int j = 0; j < 8; ++j) {
            const float v = p[(size_t)(h * 128 + j) * STRIDE];
            r[j] = __fmul_rn(v, v);
        }
        for (int i = 8; i < 128; i += 8) {
#pragma unroll
            for (int j = 0; j < 8; ++j) {
                const float v = p[(size_t)(h * 128 + i + j) * STRIDE];
                r[j] = __fadd_rn(r[j], __fmul_rn(v, v));
            }
        }
        half[h] = __fadd_rn(__fadd_rn(__fadd_rn(r[0], r[1]), __fadd_rn(r[2], r[3])),
                            __fadd_rn(__fadd_rn(r[4], r[5]), __fadd_rn(r[6], r[7])));
    }
    return __fadd_rn(half[0], half[1]);
}

// blocks 0..3: ee[k];  blocks 4..259: convert E -> bf16 hi/lo (EhW, ElW).
__global__ void prep_kernel(const float* __restrict__ emb, float* __restrict__ ee,
                            unsigned short* __restrict__ EhW, unsigned short* __restrict__ ElW) {
    if (blockIdx.x < 4) {
        const int k = blockIdx.x * 256 + threadIdx.x;
        ee[k] = np_sumsq256<1>(emb + (size_t)k * 256);
        return;
    }
    const int eid = (blockIdx.x - 4) * 256 + threadIdx.x;   // 0..65535
    const int base = eid * 4;
    float4 v = *(const float4*)(emb + base);
    const float vv[4] = {v.x, v.y, v.z, v.w};
    unsigned short h[4], l[4];
#pragma unroll
    for (int i = 0; i < 4; ++i) {
        h[i] = bf16_rne(vv[i]);
        l[i] = bf16_rne(vv[i] - bf16_to_f(h[i]));
    }
    *(ushort4*)(EhW + base) = make_ushort4(h[0], h[1], h[2], h[3]);
    *(ushort4*)(ElW + base) = make_ushort4(l[0], l[1], l[2], l[3]);
}

__global__ void xx_kernel(const float* __restrict__ x, float* __restrict__ xx) {
    const int n = blockIdx.x * blockDim.x + threadIdx.x;
    if (n >= NROWS) return;
    const int b = n >> 10, p = n & 1023;
    xx[n] = np_sumsq256<1024>(x + (size_t)b * 262144 + p);
}

// MFMA argmin: C[code][n] over 128x128 tiles; grid 2048 = 256 n-blocks x 8
// code-splits (split fastest-varying for X L3 reuse). 4 waves: w>>1 code-half,
// w&1 n-half; each wave 4x4 tiles of 16x16x32.
__global__ __launch_bounds__(256, 2)
void mfma_argmin_kernel(const float* __restrict__ x,
                        const unsigned short* __restrict__ EhW, const unsigned short* __restrict__ ElW,
                        const float* __restrict__ ee, const float* __restrict__ xx,
                        float* __restrict__ partv1, float* __restrict__ partv2,
                        int* __restrict__ parti) {
    __shared__ unsigned short Eh_s[128 * 32];  // [code][k], 64B rows
    __shared__ unsigned short El_s[128 * 32];
    __shared__ unsigned short Xh_s[128 * 32];  // [n][k]
    __shared__ unsigned short Xl_s[128 * 32];
    __shared__ float eeLds[128];
    __shared__ float mV1[128];
    __shared__ int   mI1[128];
    __shared__ float mV2[128];

    const int t = threadIdx.x;
    const int w = t >> 6, lane = t & 63;
    const int lane15 = lane & 15, quad = lane >> 4;
    const int nblk = blockIdx.x >> 3, cblk = blockIdx.x & 7;
    const int n0 = nblk * 128, c0 = cblk * 128;
    const int b = n0 >> 10, p0 = n0 & 1023;           // 128 | 1024
    const float* xb = x + (size_t)b * 262144 + p0;    // + d*1024 + p

    if (t < 128) eeLds[t] = ee[c0 + t];

    f32x4 acc[4][4];
#pragma unroll
    for (int i = 0; i < 4; ++i)
#pragma unroll
        for (int j = 0; j < 4; ++j) acc[i][j] = (f32x4){0.f, 0.f, 0.f, 0.f};

    for (int dc = 0; dc < 8; ++dc) {
        const int d0 = dc * 32;
        __syncthreads();
        // X tile: convert+transpose. p = id&127, dblk = id>>7 (8 d each).
#pragma unroll
        for (int iter = 0; iter < 2; ++iter) {
            const int id = iter * 256 + t;
            const int p = id & 127, dblk = id >> 7;
            const float* src = xb + (size_t)(d0 + dblk * 8) * 1024 + p;
            ushort8 vh, vl;
#pragma unroll
            for (int j = 0; j < 8; ++j) {
                const float v = src[(size_t)j * 1024];
                const unsigned short hh = bf16_rne(v);
                vh[j] = hh;
                vl[j] = bf16_rne(v - bf16_to_f(hh));
            }
            *(ushort8*)&Xh_s[p * 32 + dblk * 8] = vh;
            *(ushort8*)&Xl_s[p * 32 + dblk * 8] = vl;
        }
        // E tile: copy bf16 h/l. row = id>>2, 16B col = id&3.
#pragma unroll
        for (int iter = 0; iter < 2; ++iter) {
            const int id = iter * 256 + t;
            const int row = id >> 2, col = id & 3;
            const size_t g = (size_t)(c0 + row) * 256 + d0 + col * 8;
            *(ushort8*)&Eh_s[row * 32 + col * 8] = *(const ushort8*)(EhW + g);
            *(ushort8*)&El_s[row * 32 + col * 8] = *(const ushort8*)(ElW + g);
        }
        __syncthreads();
        // Fragments: operand row = lane&15, k = quad*8..+7 (16B contiguous).
        short8 ah[4], al[4], bhf[4], blf[4];
#pragma unroll
        for (int i = 0; i < 4; ++i) {
            const int cr = (w >> 1) * 64 + i * 16 + lane15;
            ah[i] = *(const short8*)&Eh_s[cr * 32 + quad * 8];
            al[i] = *(const short8*)&El_s[cr * 32 + quad * 8];
        }
#pragma unroll
        for (int j = 0; j < 4; ++j) {
            const int nr = (w & 1) * 64 + j * 16 + lane15;
            bhf[j] = *(const short8*)&Xh_s[nr * 32 + quad * 8];
            blf[j] = *(const short8*)&Xl_s[nr * 32 + quad * 8];
        }
#pragma unroll
        for (int i = 0; i < 4; ++i)
#pragma unroll
            for (int j = 0; j < 4; ++j) {
                acc[i][j] = __builtin_amdgcn_mfma_f32_16x16x32_bf16(al[i], bhf[j], acc[i][j], 0, 0, 0);
                acc[i][j] = __builtin_amdgcn_mfma_f32_16x16x32_bf16(ah[i], blf[j], acc[i][j], 0, 0, 0);
                acc[i][j] = __builtin_amdgcn_mfma_f32_16x16x32_bf16(ah[i], bhf[j], acc[i][j], 0, 0, 0);
            }
    }
    // Epilogue: per-n top-2 over this block's 128 codes.
    // C layout (16x16): col=lane&15 -> n, row=quad*4+reg -> code.
    float fb1[4], fb2[4]; int fi1[4];
#pragma unroll
    for (int j = 0; j < 4; ++j) {
        const float xxv = xx[n0 + (w & 1) * 64 + j * 16 + lane15];
        float b1 = 3.4e38f, b2 = 3.4e38f; int i1 = 0x7fffffff;
#pragma unroll
        for (int i = 0; i < 4; ++i) {
#pragma unroll
            for (int r = 0; r < 4; ++r) {
                const int cl = (w >> 1) * 64 + i * 16 + quad * 4 + r;
                const float t1 = __fadd_rn(xxv, eeLds[cl]);
                const float s = __fmaf_rn(-2.0f, acc[i][j][r], t1);
                if (s < b1) { b2 = b1; b1 = s; i1 = c0 + cl; }
                else if (s < b2) { b2 = s; }
            }
        }
#pragma unroll
        for (int off = 16; off <= 32; off <<= 1) {   // merge quads
            const float o1 = __shfl_xor(b1, off, 64);
            const int   oi = __shfl_xor(i1, off, 64);
            const float o2 = __shfl_xor(b2, off, 64);
            if (o1 < b1 || (o1 == b1 && oi < i1)) { b2 = fminf(b1, o2); b1 = o1; i1 = oi; }
            else                                  { b2 = fminf(b2, o1); }
        }
        fb1[j] = b1; fb2[j] = b2; fi1[j] = i1;
    }
    __syncthreads();
    if (w >= 2 && quad == 0) {
#pragma unroll
        for (int j = 0; j < 4; ++j) {
            const int idx = (w & 1) * 64 + j * 16 + lane15;
            mV1[idx] = fb1[j]; mI1[idx] = fi1[j]; mV2[idx] = fb2[j];
        }
    }
    __syncthreads();
    if (w < 2 && quad == 0) {
#pragma unroll
        for (int j = 0; j < 4; ++j) {
            const int idx = w * 64 + j * 16 + lane15;
            float b1 = fb1[j], b2 = fb2[j]; int i1 = fi1[j];
            const float o1 = mV1[idx]; const int oi = mI1[idx]; const float o2 = mV2[idx];
            if (o1 < b1 || (o1 == b1 && oi < i1)) { b2 = fminf(b1, o2); b1 = o1; i1 = oi; }
            else                                  { b2 = fminf(b2, o1); }
            const size_t g = (size_t)cblk * NROWS + n0 + idx;
            partv1[g] = b1; partv2[g] = b2; parti[g] = i1;
        }
    }
}

// Merge 8 splits; decided rows -> fidx/outIdx/counts; close rows -> worklist.
__global__ void combine_kernel(const float* __restrict__ partv1, const float* __restrict__ partv2,
                               const int* __restrict__ parti,
                               int* __restrict__ fidx, float* __restrict__ outIdx,
                               int* __restrict__ counts,
                               int* __restrict__ worklist, int* __restrict__ nflag) {
    const int n = blockIdx.x * blockDim.x + threadIdx.x;
    if (n >= NROWS) return;
    float b1 = 3.4e38f, b2 = 3.4e38f; int i1 = 0x7fffffff;
#pragma unroll
    for (int s = 0; s < 8; ++s) {
        const float v1 = partv1[(size_t)s * NROWS + n];
        const float v2 = partv2[(size_t)s * NROWS + n];
        const int   ii = parti [(size_t)s * NROWS + n];
        if (v1 < b1 || (v1 == b1 && ii < i1)) { b2 = fminf(b1, v2); b1 = v1; i1 = ii; }
        else                                  { b2 = fminf(b2, v1); }
    }
    if (b2 - b1 < GAP_TAU) {
        const int slot = atomicAdd(nflag, 1);
        if (slot < FLAG_CAP) { worklist[slot] = n; return; }
    }
    fidx[n] = i1;
    outIdx[n] = (float)i1;
    atomicAdd(&counts[i1], 1);
}

// np-exact rescan of flagged rows over all 1024 codes (chain dot, first-min).
__global__ __launch_bounds__(256)
void rescan_kernel(const float* __restrict__ x, const float* __restrict__ emb,
                   const float* __restrict__ ee, const float* __restrict__ xx,
                   const int* __restrict__ worklist, const int* __restrict__ nflag,
                   int* __restrict__ fidx, float* __restrict__ outIdx,
                   int* __restrict__ counts) {
    __shared__ float xrow[256];
    __shared__ float bV[4];
    __shared__ int   bI[4];
    int total = *nflag; if (total > FLAG_CAP) total = FLAG_CAP;
    for (int wq = blockIdx.x; wq < total; wq += gridDim.x) {
        const int n = worklist[wq];
        const int b = n >> 10, p = n & 1023;
        const float* xb = x + (size_t)b * 262144 + p;
        xrow[threadIdx.x] = xb[(size_t)threadIdx.x * 1024];
        __syncthreads();
        const float xxn = xx[n];
        float best = 3.4e38f; int bi = 0x7fffffff;
        for (int k = threadIdx.x; k < 1024; k += 256) {   // ascending k per thread
            const float* e = emb + (size_t)k * 256;
            float dot = 0.f;
            for (int d = 0; d < 256; ++d) dot = __fmaf_rn(e[d], xrow[d], dot);
            const float t1 = __fadd_rn(xxn, ee[k]);
            const float s = __fmaf_rn(-2.0f, dot, t1);
            if (s < best) { best = s; bi = k; }
        }
        for (int off = 32; off > 0; off >>= 1) {
            const float ov = __shfl_down(best, off, 64);
            const int   oi = __shfl_down(bi,   off, 64);
            if (ov < best || (ov == best && oi < bi)) { best = ov; bi = oi; }
        }
        const int lane = threadIdx.x & 63, wv = threadIdx.x >> 6;
        if (lane == 0) { bV[wv] = best; bI[wv] = bi; }
        __syncthreads();
        if (threadIdx.x == 0) {
            float bb = bV[0]; int ii = bI[0];
            for (int i = 1; i < 4; ++i)
                if (bV[i] < bb || (bV[i] == bb && bI[i] < ii)) { bb = bV[i]; ii = bI[i]; }
            fidx[n] = ii;
            outIdx[n] = (float)ii;
            atomicAdd(&counts[ii], 1);
        }
        __syncthreads();
    }
}

// Gather + straight-through write + sum((q-x)^2).
__global__ __launch_bounds__(256)
void quantize_kernel(const float* __restrict__ x, const float* __restrict__ emb,
                     const int* __restrict__ fidx, float* __restrict__ out,
                     float* __restrict__ sumsq) {
    const int g4 = blockIdx.x * blockDim.x + threadIdx.x;
    const int g  = g4 * 4;
    const int b  = g >> 18;
    const int d  = (g >> 10) & 255;
    const int p  = g & 1023;
    const int n  = (b << 10) | p;
    float4 xv = *(const float4*)(x + g);
    const int k0 = fidx[n], k1 = fidx[n + 1], k2 = fidx[n + 2], k3 = fidx[n + 3];
    const float q0 = emb[(size_t)k0 * 256 + d];
    const float q1 = emb[(size_t)k1 * 256 + d];
    const float q2 = emb[(size_t)k2 * 256 + d];
    const float q3 = emb[(size_t)k3 * 256 + d];
    const float e0 = q0 - xv.x, e1 = q1 - xv.y, e2 = q2 - xv.z, e3 = q3 - xv.w;
    float4 o;
    o.x = xv.x + e0; o.y = xv.y + e1; o.z = xv.z + e2; o.w = xv.w + e3;
    *(float4*)(out + g) = o;
    float loc = e0 * e0 + e1 * e1 + e2 * e2 + e3 * e3;
    for (int off = 32; off > 0; off >>= 1) loc += __shfl_down(loc, off, 64);
    __shared__ float red[4];
    const int lane = threadIdx.x & 63, wv = threadIdx.x >> 6;
    if (lane == 0) red[wv] = loc;
    __syncthreads();
    if (threadIdx.x == 0) atomicAdd(sumsq, red[0] + red[1] + red[2] + red[3]);
}

__global__ void finalize_kernel(const int* __restrict__ counts, const float* __restrict__ sumsq,
                                float* __restrict__ outScalars) {
    const int k = threadIdx.x;
    const float p = (float)counts[k] * (1.0f / 32768.0f);
    float term = p * logf(p + 1e-10f);
    for (int off = 32; off > 0; off >>= 1) term += __shfl_down(term, off, 64);
    __shared__ float red[16];
    const int lane = k & 63, wv = k >> 6;
    if (lane == 0) red[wv] = term;
    __syncthreads();
    if (k == 0) {
        float s = 0.f;
        for (int i = 0; i < 16; ++i) s += red[i];
        const float m = sumsq[0] * (1.0f / 8388608.0f);
        outScalars[0] = 1.25f * m;
        outScalars[1] = expf(-s);
    }
}

extern "C" void kernel_launch(void* const* d_in, const int* in_sizes, int n_in,
                              void* d_out, int out_size, void* d_ws, size_t ws_size,
                              hipStream_t stream) {
    const float* x   = (const float*)d_in[0];
    const float* emb = (const float*)d_in[1];
    float* out = (float*)d_out;
    float* W   = (float*)d_ws;
    float* sumsq    = W;
    int*   nflag    = (int*)(W + 1);
    int*   counts   = (int*)(W + 64);
    float* ee       = W + 1088;
    float* xx       = W + 2112;
    float* partv1   = W + 34880;
    float* partv2   = W + 297024;
    int*   parti    = (int*)(W + 559168);
    int*   worklist = (int*)(W + 821312);
    unsigned short* EhW = (unsigned short*)(W + 829504);
    unsigned short* ElW = (unsigned short*)(W + 960576);
    int*   fidx     = (int*)(W + 1091648);   // + 32768 -> total ~4.5 MB

    hipMemsetAsync(W, 0, 1088 * sizeof(float), stream);  // sumsq + nflag + counts
    prep_kernel<<<260, 256, 0, stream>>>(emb, ee, EhW, ElW);
    xx_kernel<<<128, 256, 0, stream>>>(x, xx);
    mfma_argmin_kernel<<<2048, 256, 0, stream>>>(x, EhW, ElW, ee, xx, partv1, partv2, parti);
    combine_kernel<<<128, 256, 0, stream>>>(partv1, partv2, parti, fidx, out + 8388610, counts, worklist, nflag);
    rescan_kernel<<<128, 256, 0, stream>>>(x, emb, ee, xx, worklist, nflag, fidx, out + 8388610, counts);
    quantize_kernel<<<8192, 256, 0, stream>>>(x, emb, fidx, out, sumsq);
    finalize_kernel<<<1, 1024, 0, stream>>>(counts, sumsq, out + 8388608);
}

// Round 6
// 329.241 us; speedup vs baseline: 1.4990x; 1.4990x over previous
//
#include <hip/hip_runtime.h>

// VectorQuantizer on MI355X — np-fp32-exact (R4: absmax 0.0). bf16-split MFMA
// approx scores + candidate-exact-compare (np chain) for near-tie rows.
//
// np ref (verified bit-exact): xx/ee = pairwise fp32 sums; dot = d-sequential
// fp32 fma chain; s = fl(fl(xx+ee) - 2*dot); argmin = first minimum.
// Scores sit on a ~3e-5 grid (xx+ee ~ 256-340) -> near-ties pervasive
// (R5: ~25% of rows within 3 ulps). Decision architecture:
//   argmin (MFMA):   per-(row,128-code-split) top-3 values, top-2 indices
//   combine:         global b1; if any split's v3 within TAU of b1 -> listB
//                    (possible hidden candidate); else candidates = known
//                    (v,i) with v-b1<TAU: 1 -> decided, <=14 -> listA
//   exact_kernel:    np-exact chain score per candidate, first-min -> listA rows
//   rescanB_kernel:  np-exact full 1024-code scan -> listB rows (rare)
// Correctness: |s'_mfma - s_np| <= ~5e-6 << TAU=1e-4; within-TAU true winner
// is rank<=2 in its split (else v3 guard trips) -> always exact-compared.
//
// ws layout (float units):
//   0 sumsq | 1 nA | 2 nB | 64 counts[1024] | 1088 ee[1024] | 2112 xx[32768]
//   34880 pv1 | 297024 pi1 | 559168 pv2 | 821312 pi2 | 1083456 pv3   [8*32768 ea]
//   1345600 listA[16384*16 int] | 1476672 listB[8192 int]
//   1484864 EhW ushort[262144] | 1615936 ElW ushort[262144]
//   1747008 fidx[32768]  -> ~7.1 MB total.

#define NROWS 32768
#define CAPA 16384
#define CAPB 8192
#define GAP_TAU 1e-4f

typedef __attribute__((ext_vector_type(8))) short short8;
typedef __attribute__((ext_vector_type(8))) unsigned short ushort8;
typedef __attribute__((ext_vector_type(4))) float f32x4;

struct Top3 { float v1, v2, v3; int i1, i2; };

// Merge two sorted top-3s (values sorted asc; indices on slots 1,2).
__device__ __forceinline__ void top3_merge(Top3& a, const Top3& o) {
    Top3 r;
    if (o.v1 < a.v1 || (o.v1 == a.v1 && o.i1 < a.i1)) {
        r.v1 = o.v1; r.i1 = o.i1;
        if (a.v1 < o.v2 || (a.v1 == o.v2 && a.i1 < o.i2)) {
            r.v2 = a.v1; r.i2 = a.i1; r.v3 = fminf(o.v2, a.v2);
        } else {
            r.v2 = o.v2; r.i2 = o.i2; r.v3 = fminf(a.v1, o.v3);
        }
    } else {
        r.v1 = a.v1; r.i1 = a.i1;
        if (o.v1 < a.v2 || (o.v1 == a.v2 && o.i1 < a.i2)) {
            r.v2 = o.v1; r.i2 = o.i1; r.v3 = fminf(a.v2, o.v2);
        } else {
            r.v2 = a.v2; r.i2 = a.i2; r.v3 = fminf(o.v1, a.v3);
        }
    }
    a = r;
}

__device__ __forceinline__ unsigned short bf16_rne(float v) {
    unsigned int u = __float_as_uint(v);
    return (unsigned short)((u + 0x7fffu + ((u >> 16) & 1u)) >> 16);
}
__device__ __forceinline__ float bf16_to_f(unsigned short h) {
    return __uint_as_float(((unsigned int)h) << 16);
}

// numpy pairwise sum of squares over 256: pw128+pw128, 8-lane accumulators.
template <int STRIDE>
__device__ __forceinline__ float np_sumsq256(const float* __restrict__ p) {
    float half[2];
#pragma unroll
    for (int h = 0; h < 2; ++h) {
        float r[8];
#pragma unroll
        for (int j = 0; j < 8; ++j) {
            const float v = p[(size_t)(h * 128 + j) * STRIDE];
            r[j] = __fmul_rn(v, v);
        }
        for (int i = 8; i < 128; i += 8) {
#pragma unroll
            for (int j = 0; j < 8; ++j) {
                const float v = p[(size_t)(h * 128 + i + j) * STRIDE];
                r[j] = __fadd_rn(r[j], __fmul_rn(v, v));
            }
        }
        half[h] = __fadd_rn(__fadd_rn(__fadd_rn(r[0], r[1]), __fadd_rn(r[2], r[3])),
                            __fadd_rn(__fadd_rn(r[4], r[5]), __fadd_rn(r[6], r[7])));
    }
    return __fadd_rn(half[0], half[1]);
}

// blocks 0..3: ee; 4..259: E -> bf16 h/l; 260..387: xx.
__global__ void prep_kernel(const float* __restrict__ emb, const float* __restrict__ x,
                            float* __restrict__ ee, float* __restrict__ xx,
                            unsigned short* __restrict__ EhW, unsigned short* __restrict__ ElW) {
    if (blockIdx.x < 4) {
        const int k = blockIdx.x * 256 + threadIdx.x;
        ee[k] = np_sumsq256<1>(emb + (size_t)k * 256);
        return;
    }
    if (blockIdx.x >= 260) {
        const int n = (blockIdx.x - 260) * 256 + threadIdx.x;
        const int b = n >> 10, p = n & 1023;
        xx[n] = np_sumsq256<1024>(x + (size_t)b * 262144 + p);
        return;
    }
    const int eid = (blockIdx.x - 4) * 256 + threadIdx.x;   // 0..65535
    const int base = eid * 4;
    float4 v = *(const float4*)(emb + base);
    const float vv[4] = {v.x, v.y, v.z, v.w};
    unsigned short h[4], l[4];
#pragma unroll
    for (int i = 0; i < 4; ++i) {
        h[i] = bf16_rne(vv[i]);
        l[i] = bf16_rne(vv[i] - bf16_to_f(h[i]));
    }
    *(ushort4*)(EhW + base) = make_ushort4(h[0], h[1], h[2], h[3]);
    *(ushort4*)(ElW + base) = make_ushort4(l[0], l[1], l[2], l[3]);
}

// MFMA argmin: 128 codes x 128 rows per block; grid 2048 = 256 n-blocks x 8
// code-splits. 4 waves: w>>1 code-half, w&1 n-half; 4x4 tiles of 16x16x32.
// Epilogue: per-row top-3 values + top-2 indices within the split.
__global__ __launch_bounds__(256, 2)
void mfma_argmin_kernel(const float* __restrict__ x,
                        const unsigned short* __restrict__ EhW, const unsigned short* __restrict__ ElW,
                        const float* __restrict__ ee, const float* __restrict__ xx,
                        float* __restrict__ pv1, int* __restrict__ pi1,
                        float* __restrict__ pv2, int* __restrict__ pi2,
                        float* __restrict__ pv3) {
    __shared__ unsigned short Eh_s[128 * 32];  // [code][k], 64B rows
    __shared__ unsigned short El_s[128 * 32];
    __shared__ unsigned short Xh_s[128 * 32];  // [n][k]
    __shared__ unsigned short Xl_s[128 * 32];
    __shared__ float eeLds[128];
    __shared__ float mV1[128], mV2[128], mV3[128];
    __shared__ int   mI1[128], mI2[128];

    const int t = threadIdx.x;
    const int w = t >> 6, lane = t & 63;
    const int lane15 = lane & 15, quad = lane >> 4;
    const int nblk = blockIdx.x >> 3, cblk = blockIdx.x & 7;
    const int n0 = nblk * 128, c0 = cblk * 128;
    const int b = n0 >> 10, p0 = n0 & 1023;           // 128 | 1024
    const float* xb = x + (size_t)b * 262144 + p0;    // + d*1024 + p

    if (t < 128) eeLds[t] = ee[c0 + t];

    f32x4 acc[4][4];
#pragma unroll
    for (int i = 0; i < 4; ++i)
#pragma unroll
        for (int j = 0; j < 4; ++j) acc[i][j] = (f32x4){0.f, 0.f, 0.f, 0.f};

    for (int dc = 0; dc < 8; ++dc) {
        const int d0 = dc * 32;
        __syncthreads();
        // X tile: convert+transpose. p = id&127, dblk = id>>7 (8 d each).
#pragma unroll
        for (int iter = 0; iter < 2; ++iter) {
            const int id = iter * 256 + t;
            const int p = id & 127, dblk = id >> 7;
            const float* src = xb + (size_t)(d0 + dblk * 8) * 1024 + p;
            ushort8 vh, vl;
#pragma unroll
            for (int j = 0; j < 8; ++j) {
                const float v = src[(size_t)j * 1024];
                const unsigned short hh = bf16_rne(v);
                vh[j] = hh;
                vl[j] = bf16_rne(v - bf16_to_f(hh));
            }
            *(ushort8*)&Xh_s[p * 32 + dblk * 8] = vh;
            *(ushort8*)&Xl_s[p * 32 + dblk * 8] = vl;
        }
        // E tile: copy bf16 h/l. row = id>>2, 16B col = id&3.
#pragma unroll
        for (int iter = 0; iter < 2; ++iter) {
            const int id = iter * 256 + t;
            const int row = id >> 2, col = id & 3;
            const size_t g = (size_t)(c0 + row) * 256 + d0 + col * 8;
            *(ushort8*)&Eh_s[row * 32 + col * 8] = *(const ushort8*)(EhW + g);
            *(ushort8*)&El_s[row * 32 + col * 8] = *(const ushort8*)(ElW + g);
        }
        __syncthreads();
        short8 ah[4], al[4], bhf[4], blf[4];
#pragma unroll
        for (int i = 0; i < 4; ++i) {
            const int cr = (w >> 1) * 64 + i * 16 + lane15;
            ah[i] = *(const short8*)&Eh_s[cr * 32 + quad * 8];
            al[i] = *(const short8*)&El_s[cr * 32 + quad * 8];
        }
#pragma unroll
        for (int j = 0; j < 4; ++j) {
            const int nr = (w & 1) * 64 + j * 16 + lane15;
            bhf[j] = *(const short8*)&Xh_s[nr * 32 + quad * 8];
            blf[j] = *(const short8*)&Xl_s[nr * 32 + quad * 8];
        }
#pragma unroll
        for (int i = 0; i < 4; ++i)
#pragma unroll
            for (int j = 0; j < 4; ++j) {
                acc[i][j] = __builtin_amdgcn_mfma_f32_16x16x32_bf16(al[i], bhf[j], acc[i][j], 0, 0, 0);
                acc[i][j] = __builtin_amdgcn_mfma_f32_16x16x32_bf16(ah[i], blf[j], acc[i][j], 0, 0, 0);
                acc[i][j] = __builtin_amdgcn_mfma_f32_16x16x32_bf16(ah[i], bhf[j], acc[i][j], 0, 0, 0);
            }
    }
    // Epilogue: per-n top-3 over this block's 128 codes.
    // C layout (16x16): col=lane&15 -> n, row=quad*4+reg -> code.
    Top3 tj[4];
#pragma unroll
    for (int j = 0; j < 4; ++j) {
        const float xxv = xx[n0 + (w & 1) * 64 + j * 16 + lane15];
        Top3 tt; tt.v1 = tt.v2 = tt.v3 = 3.4e38f; tt.i1 = tt.i2 = 0x7fffffff;
#pragma unroll
        for (int i = 0; i < 4; ++i)
#pragma unroll
            for (int r = 0; r < 4; ++r) {
                const int cl = (w >> 1) * 64 + i * 16 + quad * 4 + r;
                const float t1 = __fadd_rn(xxv, eeLds[cl]);
                const float s = __fmaf_rn(-2.0f, acc[i][j][r], t1);
                const int kk = c0 + cl;
                if (s < tt.v1) { tt.v3 = tt.v2; tt.v2 = tt.v1; tt.i2 = tt.i1; tt.v1 = s; tt.i1 = kk; }
                else if (s < tt.v2) { tt.v3 = tt.v2; tt.v2 = s; tt.i2 = kk; }
                else if (s < tt.v3) { tt.v3 = s; }
            }
#pragma unroll
        for (int off = 16; off <= 32; off <<= 1) {   // merge quads
            Top3 o;
            o.v1 = __shfl_xor(tt.v1, off, 64); o.i1 = __shfl_xor(tt.i1, off, 64);
            o.v2 = __shfl_xor(tt.v2, off, 64); o.i2 = __shfl_xor(tt.i2, off, 64);
            o.v3 = __shfl_xor(tt.v3, off, 64);
            top3_merge(tt, o);
        }
        tj[j] = tt;
    }
    __syncthreads();
    if (w >= 2 && quad == 0) {
#pragma unroll
        for (int j = 0; j < 4; ++j) {
            const int idx = (w & 1) * 64 + j * 16 + lane15;
            mV1[idx] = tj[j].v1; mI1[idx] = tj[j].i1;
            mV2[idx] = tj[j].v2; mI2[idx] = tj[j].i2;
            mV3[idx] = tj[j].v3;
        }
    }
    __syncthreads();
    if (w < 2 && quad == 0) {
#pragma unroll
        for (int j = 0; j < 4; ++j) {
            const int idx = w * 64 + j * 16 + lane15;
            Top3 tt = tj[j];
            Top3 o; o.v1 = mV1[idx]; o.i1 = mI1[idx]; o.v2 = mV2[idx]; o.i2 = mI2[idx]; o.v3 = mV3[idx];
            top3_merge(tt, o);
            const size_t g = (size_t)cblk * NROWS + n0 + idx;
            pv1[g] = tt.v1; pi1[g] = tt.i1; pv2[g] = tt.v2; pi2[g] = tt.i2; pv3[g] = tt.v3;
        }
    }
}

// Merge 8 splits: decided rows -> output; ambiguous -> listA (candidates) or
// listB (possible hidden candidate / too many).
__global__ void combine_kernel(const float* __restrict__ pv1, const int* __restrict__ pi1,
                               const float* __restrict__ pv2, const int* __restrict__ pi2,
                               const float* __restrict__ pv3,
                               int* __restrict__ fidx, float* __restrict__ outIdx,
                               int* __restrict__ counts,
                               int* __restrict__ listA, int* __restrict__ nA,
                               int* __restrict__ listB, int* __restrict__ nB) {
    const int n = blockIdx.x * blockDim.x + threadIdx.x;
    if (n >= NROWS) return;
    float v1[8], v2[8]; int i1[8], i2[8];
    float b1 = 3.4e38f, v3m = 3.4e38f; int bi = 0x7fffffff;
#pragma unroll
    for (int s = 0; s < 8; ++s) {
        v1[s] = pv1[(size_t)s * NROWS + n]; i1[s] = pi1[(size_t)s * NROWS + n];
        v2[s] = pv2[(size_t)s * NROWS + n]; i2[s] = pi2[(size_t)s * NROWS + n];
        v3m = fminf(v3m, pv3[(size_t)s * NROWS + n]);
        if (v1[s] < b1 || (v1[s] == b1 && i1[s] < bi)) { b1 = v1[s]; bi = i1[s]; }
    }
    if (v3m - b1 < GAP_TAU) {            // a split may hide a 3rd candidate
        const int s = atomicAdd(nB, 1);
        if (s < CAPB) { listB[s] = n; return; }
    } else {
        int ks[16]; int cnt = 0;
#pragma unroll
        for (int s = 0; s < 8; ++s) {
            if (v1[s] - b1 < GAP_TAU) ks[cnt++] = i1[s];
            if (v2[s] - b1 < GAP_TAU) ks[cnt++] = i2[s];
        }
        if (cnt > 1) {
            if (cnt <= 14) {
                const int slot = atomicAdd(nA, 1);
                if (slot < CAPA) {
                    int* e = listA + slot * 16;
                    e[0] = n; e[1] = cnt;
                    for (int c = 0; c < cnt; ++c) e[2 + c] = ks[c];
                    return;
                }
            } else {
                const int s = atomicAdd(nB, 1);
                if (s < CAPB) { listB[s] = n; return; }
            }
        }
    }
    fidx[n] = bi;                        // decided (or cap-overflow fallback)
    outIdx[n] = (float)bi;
    atomicAdd(&counts[bi], 1);
}

// np-exact chain score for each listed candidate; first-min wins.
__global__ __launch_bounds__(256)
void exact_kernel(const float* __restrict__ x, const float* __restrict__ emb,
                  const float* __restrict__ ee, const float* __restrict__ xx,
                  const int* __restrict__ listA, const int* __restrict__ nA,
                  int* __restrict__ fidx, float* __restrict__ outIdx,
                  int* __restrict__ counts) {
    int total = *nA; if (total > CAPA) total = CAPA;
    const int sub = threadIdx.x >> 4;     // 16 entries per block
    const int li  = threadIdx.x & 15;
    for (int e = blockIdx.x * 16 + sub; e < total; e += gridDim.x * 16) {
        const int* ent = listA + (size_t)e * 16;
        const int n = ent[0], cnt = ent[1];
        float s = 3.4e38f; int k = 0x7fffffff;
        if (li < cnt) {
            k = ent[2 + li];
            const int b = n >> 10, p = n & 1023;
            const float* xr = x + (size_t)b * 262144 + p;
            const float* er = emb + (size_t)k * 256;
            float dot = 0.f;
#pragma unroll 8
            for (int d = 0; d < 256; ++d)
                dot = __fmaf_rn(er[d], xr[(size_t)d * 1024], dot);
            s = __fmaf_rn(-2.0f, dot, __fadd_rn(xx[n], ee[k]));
        }
#pragma unroll
        for (int off = 1; off < 16; off <<= 1) {
            const float ov = __shfl_xor(s, off, 16);
            const int   ok = __shfl_xor(k, off, 16);
            if (ov < s || (ov == s && ok < k)) { s = ov; k = ok; }
        }
        if (li == 0) { fidx[n] = k; outIdx[n] = (float)k; atomicAdd(&counts[k], 1); }
    }
}

// np-exact full rescan over all 1024 codes for listB rows (rare).
__global__ __launch_bounds__(256)
void rescanB_kernel(const float* __restrict__ x, const float* __restrict__ emb,
                    const float* __restrict__ ee, const float* __restrict__ xx,
                    const int* __restrict__ listB, const int* __restrict__ nB,
                    int* __restrict__ fidx, float* __restrict__ outIdx,
                    int* __restrict__ counts) {
    __shared__ float xrow[256];
    __shared__ float bV[4];
    __shared__ int   bI[4];
    int total = *nB; if (total > CAPB) total = CAPB;
    for (int wq = blockIdx.x; wq < total; wq += gridDim.x) {
        const int n = listB[wq];
        const int b = n >> 10, p = n & 1023;
        const float* xb = x + (size_t)b * 262144 + p;
        xrow[threadIdx.x] = xb[(size_t)threadIdx.x * 1024];
        __syncthreads();
        const float xxn = xx[n];
        float best = 3.4e38f; int bi = 0x7fffffff;
        for (int k = threadIdx.x; k < 1024; k += 256) {   // ascending k per thread
            const float* e = emb + (size_t)k * 256;
            float dot = 0.f;
            for (int d = 0; d < 256; ++d) dot = __fmaf_rn(e[d], xrow[d], dot);
            const float t1 = __fadd_rn(xxn, ee[k]);
            const float s = __fmaf_rn(-2.0f, dot, t1);
            if (s < best) { best = s; bi = k; }
        }
        for (int off = 32; off > 0; off >>= 1) {
            const float ov = __shfl_down(best, off, 64);
            const int   oi = __shfl_down(bi,   off, 64);
            if (ov < best || (ov == best && oi < bi)) { best = ov; bi = oi; }
        }
        const int lane = threadIdx.x & 63, wv = threadIdx.x >> 6;
        if (lane == 0) { bV[wv] = best; bI[wv] = bi; }
        __syncthreads();
        if (threadIdx.x == 0) {
            float bb = bV[0]; int ii = bI[0];
            for (int i = 1; i < 4; ++i)
                if (bV[i] < bb || (bV[i] == bb && bI[i] < ii)) { bb = bV[i]; ii = bI[i]; }
            fidx[n] = ii;
            outIdx[n] = (float)ii;
            atomicAdd(&counts[ii], 1);
        }
        __syncthreads();
    }
}

// Gather + straight-through write + sum((q-x)^2).
__global__ __launch_bounds__(256)
void quantize_kernel(const float* __restrict__ x, const float* __restrict__ emb,
                     const int* __restrict__ fidx, float* __restrict__ out,
                     float* __restrict__ sumsq) {
    const int g4 = blockIdx.x * blockDim.x + threadIdx.x;
    const int g  = g4 * 4;
    const int b  = g >> 18;
    const int d  = (g >> 10) & 255;
    const int p  = g & 1023;
    const int n  = (b << 10) | p;
    float4 xv = *(const float4*)(x + g);
    const int k0 = fidx[n], k1 = fidx[n + 1], k2 = fidx[n + 2], k3 = fidx[n + 3];
    const float q0 = emb[(size_t)k0 * 256 + d];
    const float q1 = emb[(size_t)k1 * 256 + d];
    const float q2 = emb[(size_t)k2 * 256 + d];
    const float q3 = emb[(size_t)k3 * 256 + d];
    const float e0 = q0 - xv.x, e1 = q1 - xv.y, e2 = q2 - xv.z, e3 = q3 - xv.w;
    float4 o;
    o.x = xv.x + e0; o.y = xv.y + e1; o.z = xv.z + e2; o.w = xv.w + e3;
    *(float4*)(out + g) = o;
    float loc = e0 * e0 + e1 * e1 + e2 * e2 + e3 * e3;
    for (int off = 32; off > 0; off >>= 1) loc += __shfl_down(loc, off, 64);
    __shared__ float red[4];
    const int lane = threadIdx.x & 63, wv = threadIdx.x >> 6;
    if (lane == 0) red[wv] = loc;
    __syncthreads();
    if (threadIdx.x == 0) atomicAdd(sumsq, red[0] + red[1] + red[2] + red[3]);
}

__global__ void finalize_kernel(const int* __restrict__ counts, const float* __restrict__ sumsq,
                                float* __restrict__ outScalars) {
    const int k = threadIdx.x;
    const float p = (float)counts[k] * (1.0f / 32768.0f);
    float term = p * logf(p + 1e-10f);
    for (int off = 32; off > 0; off >>= 1) term += __shfl_down(term, off, 64);
    __shared__ float red[16];
    const int lane = k & 63, wv = k >> 6;
    if (lane == 0) red[wv] = term;
    __syncthreads();
    if (k == 0) {
        float s = 0.f;
        for (int i = 0; i < 16; ++i) s += red[i];
        const float m = sumsq[0] * (1.0f / 8388608.0f);
        outScalars[0] = 1.25f * m;
        outScalars[1] = expf(-s);
    }
}

extern "C" void kernel_launch(void* const* d_in, const int* in_sizes, int n_in,
                              void* d_out, int out_size, void* d_ws, size_t ws_size,
                              hipStream_t stream) {
    const float* x   = (const float*)d_in[0];
    const float* emb = (const float*)d_in[1];
    float* out = (float*)d_out;
    float* W   = (float*)d_ws;
    float* sumsq = W;
    int*   nA    = (int*)(W + 1);
    int*   nB    = (int*)(W + 2);
    int*   counts = (int*)(W + 64);
    float* ee    = W + 1088;
    float* xx    = W + 2112;
    float* pv1   = W + 34880;
    int*   pi1   = (int*)(W + 297024);
    float* pv2   = W + 559168;
    int*   pi2   = (int*)(W + 821312);
    float* pv3   = W + 1083456;
    int*   listA = (int*)(W + 1345600);
    int*   listB = (int*)(W + 1476672);
    unsigned short* EhW = (unsigned short*)(W + 1484864);
    unsigned short* ElW = (unsigned short*)(W + 1615936);
    int*   fidx  = (int*)(W + 1747008);

    hipMemsetAsync(W, 0, 1088 * sizeof(float), stream);  // sumsq + nA/nB + counts
    prep_kernel<<<388, 256, 0, stream>>>(emb, x, ee, xx, EhW, ElW);
    mfma_argmin_kernel<<<2048, 256, 0, stream>>>(x, EhW, ElW, ee, xx, pv1, pi1, pv2, pi2, pv3);
    combine_kernel<<<128, 256, 0, stream>>>(pv1, pi1, pv2, pi2, pv3, fidx, out + 8388610,
                                            counts, listA, nA, listB, nB);
    exact_kernel<<<256, 256, 0, stream>>>(x, emb, ee, xx, listA, nA, fidx, out + 8388610, counts);
    rescanB_kernel<<<256, 256, 0, stream>>>(x, emb, ee, xx, listB, nB, fidx, out + 8388610, counts);
    quantize_kernel<<<8192, 256, 0, stream>>>(x, emb, fidx, out, sumsq);
    finalize_kernel<<<1, 1024, 0, stream>>>(counts, sumsq, out + 8388608);
}

// Round 7
// 234.301 us; speedup vs baseline: 2.1065x; 1.4052x over previous
//
#include <hip/hip_runtime.h>

// VectorQuantizer on MI355X — np-fp32-exact (R4: absmax 0.0). bf16-split MFMA
// approx scores + candidate-exact-compare (np chain) for near-tie rows.
//
// np ref (verified bit-exact): xx/ee = pairwise fp32 sums; dot = d-sequential
// fp32 fma chain; s = fl(fl(xx+ee) - 2*dot); argmin = first minimum.
// Scores sit on a ~3e-5 grid (xx+ee ~ 256-340) -> near-ties pervasive.
//   argmin (MFMA):   per-(row,128-code-split) top-3 values, top-2 indices
//   combine:         global b1; v3-guard -> listB; else known candidates
//                    within TAU: 1 -> decided, <=14 -> listA
//   exact_kernel:    np-exact chain score per candidate (listA)
//   rescanB_kernel:  np-exact full scan (listB, rare)
// quantize (R7): one thread = one pixel x 64 d. Code row read as sequential
// float4 gathers (each 64B line fetched once, fully used) instead of R6's
// 64-lines-per-instruction 4B scatter (110us -> ~15us predicted).
//
// ws layout (float units):
//   0 sumsq | 1 nA | 2 nB | 64 counts[1024] | 1088 ee[1024] | 2112 xx[32768]
//   34880 pv1 | 297024 pi1 | 559168 pv2 | 821312 pi2 | 1083456 pv3   [8*32768 ea]
//   1345600 listA[16384*16 int] | 1476672 listB[8192 int]
//   1484864 EhW ushort[262144] | 1615936 ElW ushort[262144]
//   1747008 fidx[32768]  -> ~7.1 MB total.

#define NROWS 32768
#define CAPA 16384
#define CAPB 8192
#define GAP_TAU 1e-4f

typedef __attribute__((ext_vector_type(8))) short short8;
typedef __attribute__((ext_vector_type(8))) unsigned short ushort8;
typedef __attribute__((ext_vector_type(4))) float f32x4;

struct Top3 { float v1, v2, v3; int i1, i2; };

// Merge two sorted top-3s (values sorted asc; indices on slots 1,2).
__device__ __forceinline__ void top3_merge(Top3& a, const Top3& o) {
    Top3 r;
    if (o.v1 < a.v1 || (o.v1 == a.v1 && o.i1 < a.i1)) {
        r.v1 = o.v1; r.i1 = o.i1;
        if (a.v1 < o.v2 || (a.v1 == o.v2 && a.i1 < o.i2)) {
            r.v2 = a.v1; r.i2 = a.i1; r.v3 = fminf(o.v2, a.v2);
        } else {
            r.v2 = o.v2; r.i2 = o.i2; r.v3 = fminf(a.v1, o.v3);
        }
    } else {
        r.v1 = a.v1; r.i1 = a.i1;
        if (o.v1 < a.v2 || (o.v1 == a.v2 && o.i1 < a.i2)) {
            r.v2 = o.v1; r.i2 = o.i1; r.v3 = fminf(a.v2, o.v2);
        } else {
            r.v2 = a.v2; r.i2 = a.i2; r.v3 = fminf(o.v1, a.v3);
        }
    }
    a = r;
}

__device__ __forceinline__ unsigned short bf16_rne(float v) {
    unsigned int u = __float_as_uint(v);
    return (unsigned short)((u + 0x7fffu + ((u >> 16) & 1u)) >> 16);
}
__device__ __forceinline__ float bf16_to_f(unsigned short h) {
    return __uint_as_float(((unsigned int)h) << 16);
}

// numpy pairwise sum of squares over 256: pw128+pw128, 8-lane accumulators.
template <int STRIDE>
__device__ __forceinline__ float np_sumsq256(const float* __restrict__ p) {
    float half[2];
#pragma unroll
    for (int h = 0; h < 2; ++h) {
        float r[8];
#pragma unroll
        for (int j = 0; j < 8; ++j) {
            const float v = p[(size_t)(h * 128 + j) * STRIDE];
            r[j] = __fmul_rn(v, v);
        }
        for (int i = 8; i < 128; i += 8) {
#pragma unroll
            for (int j = 0; j < 8; ++j) {
                const float v = p[(size_t)(h * 128 + i + j) * STRIDE];
                r[j] = __fadd_rn(r[j], __fmul_rn(v, v));
            }
        }
        half[h] = __fadd_rn(__fadd_rn(__fadd_rn(r[0], r[1]), __fadd_rn(r[2], r[3])),
                            __fadd_rn(__fadd_rn(r[4], r[5]), __fadd_rn(r[6], r[7])));
    }
    return __fadd_rn(half[0], half[1]);
}

// blocks 0..3: ee; 4..259: E -> bf16 h/l; 260..387: xx.
__global__ void prep_kernel(const float* __restrict__ emb, const float* __restrict__ x,
                            float* __restrict__ ee, float* __restrict__ xx,
                            unsigned short* __restrict__ EhW, unsigned short* __restrict__ ElW) {
    if (blockIdx.x < 4) {
        const int k = blockIdx.x * 256 + threadIdx.x;
        ee[k] = np_sumsq256<1>(emb + (size_t)k * 256);
        return;
    }
    if (blockIdx.x >= 260) {
        const int n = (blockIdx.x - 260) * 256 + threadIdx.x;
        const int b = n >> 10, p = n & 1023;
        xx[n] = np_sumsq256<1024>(x + (size_t)b * 262144 + p);
        return;
    }
    const int eid = (blockIdx.x - 4) * 256 + threadIdx.x;   // 0..65535
    const int base = eid * 4;
    float4 v = *(const float4*)(emb + base);
    const float vv[4] = {v.x, v.y, v.z, v.w};
    unsigned short h[4], l[4];
#pragma unroll
    for (int i = 0; i < 4; ++i) {
        h[i] = bf16_rne(vv[i]);
        l[i] = bf16_rne(vv[i] - bf16_to_f(h[i]));
    }
    *(ushort4*)(EhW + base) = make_ushort4(h[0], h[1], h[2], h[3]);
    *(ushort4*)(ElW + base) = make_ushort4(l[0], l[1], l[2], l[3]);
}

// MFMA argmin: 128 codes x 128 rows per block; grid 2048 = 256 n-blocks x 8
// code-splits. 4 waves: w>>1 code-half, w&1 n-half; 4x4 tiles of 16x16x32.
// Epilogue: per-row top-3 values + top-2 indices within the split.
__global__ __launch_bounds__(256, 2)
void mfma_argmin_kernel(const float* __restrict__ x,
                        const unsigned short* __restrict__ EhW, const unsigned short* __restrict__ ElW,
                        const float* __restrict__ ee, const float* __restrict__ xx,
                        float* __restrict__ pv1, int* __restrict__ pi1,
                        float* __restrict__ pv2, int* __restrict__ pi2,
                        float* __restrict__ pv3) {
    __shared__ unsigned short Eh_s[128 * 32];  // [code][k], 64B rows
    __shared__ unsigned short El_s[128 * 32];
    __shared__ unsigned short Xh_s[128 * 32];  // [n][k]
    __shared__ unsigned short Xl_s[128 * 32];
    __shared__ float eeLds[128];
    __shared__ float mV1[128], mV2[128], mV3[128];
    __shared__ int   mI1[128], mI2[128];

    const int t = threadIdx.x;
    const int w = t >> 6, lane = t & 63;
    const int lane15 = lane & 15, quad = lane >> 4;
    const int nblk = blockIdx.x >> 3, cblk = blockIdx.x & 7;
    const int n0 = nblk * 128, c0 = cblk * 128;
    const int b = n0 >> 10, p0 = n0 & 1023;           // 128 | 1024
    const float* xb = x + (size_t)b * 262144 + p0;    // + d*1024 + p

    if (t < 128) eeLds[t] = ee[c0 + t];

    f32x4 acc[4][4];
#pragma unroll
    for (int i = 0; i < 4; ++i)
#pragma unroll
        for (int j = 0; j < 4; ++j) acc[i][j] = (f32x4){0.f, 0.f, 0.f, 0.f};

    for (int dc = 0; dc < 8; ++dc) {
        const int d0 = dc * 32;
        __syncthreads();
        // X tile: convert+transpose. p = id&127, dblk = id>>7 (8 d each).
#pragma unroll
        for (int iter = 0; iter < 2; ++iter) {
            const int id = iter * 256 + t;
            const int p = id & 127, dblk = id >> 7;
            const float* src = xb + (size_t)(d0 + dblk * 8) * 1024 + p;
            ushort8 vh, vl;
#pragma unroll
            for (int j = 0; j < 8; ++j) {
                const float v = src[(size_t)j * 1024];
                const unsigned short hh = bf16_rne(v);
                vh[j] = hh;
                vl[j] = bf16_rne(v - bf16_to_f(hh));
            }
            *(ushort8*)&Xh_s[p * 32 + dblk * 8] = vh;
            *(ushort8*)&Xl_s[p * 32 + dblk * 8] = vl;
        }
        // E tile: copy bf16 h/l. row = id>>2, 16B col = id&3.
#pragma unroll
        for (int iter = 0; iter < 2; ++iter) {
            const int id = iter * 256 + t;
            const int row = id >> 2, col = id & 3;
            const size_t g = (size_t)(c0 + row) * 256 + d0 + col * 8;
            *(ushort8*)&Eh_s[row * 32 + col * 8] = *(const ushort8*)(EhW + g);
            *(ushort8*)&El_s[row * 32 + col * 8] = *(const ushort8*)(ElW + g);
        }
        __syncthreads();
        short8 ah[4], al[4], bhf[4], blf[4];
#pragma unroll
        for (int i = 0; i < 4; ++i) {
            const int cr = (w >> 1) * 64 + i * 16 + lane15;
            ah[i] = *(const short8*)&Eh_s[cr * 32 + quad * 8];
            al[i] = *(const short8*)&El_s[cr * 32 + quad * 8];
        }
#pragma unroll
        for (int j = 0; j < 4; ++j) {
            const int nr = (w & 1) * 64 + j * 16 + lane15;
            bhf[j] = *(const short8*)&Xh_s[nr * 32 + quad * 8];
            blf[j] = *(const short8*)&Xl_s[nr * 32 + quad * 8];
        }
#pragma unroll
        for (int i = 0; i < 4; ++i)
#pragma unroll
            for (int j = 0; j < 4; ++j) {
                acc[i][j] = __builtin_amdgcn_mfma_f32_16x16x32_bf16(al[i], bhf[j], acc[i][j], 0, 0, 0);
                acc[i][j] = __builtin_amdgcn_mfma_f32_16x16x32_bf16(ah[i], blf[j], acc[i][j], 0, 0, 0);
                acc[i][j] = __builtin_amdgcn_mfma_f32_16x16x32_bf16(ah[i], bhf[j], acc[i][j], 0, 0, 0);
            }
    }
    // Epilogue: per-n top-3 over this block's 128 codes.
    // C layout (16x16): col=lane&15 -> n, row=quad*4+reg -> code.
    Top3 tj[4];
#pragma unroll
    for (int j = 0; j < 4; ++j) {
        const float xxv = xx[n0 + (w & 1) * 64 + j * 16 + lane15];
        Top3 tt; tt.v1 = tt.v2 = tt.v3 = 3.4e38f; tt.i1 = tt.i2 = 0x7fffffff;
#pragma unroll
        for (int i = 0; i < 4; ++i)
#pragma unroll
            for (int r = 0; r < 4; ++r) {
                const int cl = (w >> 1) * 64 + i * 16 + quad * 4 + r;
                const float t1 = __fadd_rn(xxv, eeLds[cl]);
                const float s = __fmaf_rn(-2.0f, acc[i][j][r], t1);
                const int kk = c0 + cl;
                if (s < tt.v1) { tt.v3 = tt.v2; tt.v2 = tt.v1; tt.i2 = tt.i1; tt.v1 = s; tt.i1 = kk; }
                else if (s < tt.v2) { tt.v3 = tt.v2; tt.v2 = s; tt.i2 = kk; }
                else if (s < tt.v3) { tt.v3 = s; }
            }
#pragma unroll
        for (int off = 16; off <= 32; off <<= 1) {   // merge quads
            Top3 o;
            o.v1 = __shfl_xor(tt.v1, off, 64); o.i1 = __shfl_xor(tt.i1, off, 64);
            o.v2 = __shfl_xor(tt.v2, off, 64); o.i2 = __shfl_xor(tt.i2, off, 64);
            o.v3 = __shfl_xor(tt.v3, off, 64);
            top3_merge(tt, o);
        }
        tj[j] = tt;
    }
    __syncthreads();
    if (w >= 2 && quad == 0) {
#pragma unroll
        for (int j = 0; j < 4; ++j) {
            const int idx = (w & 1) * 64 + j * 16 + lane15;
            mV1[idx] = tj[j].v1; mI1[idx] = tj[j].i1;
            mV2[idx] = tj[j].v2; mI2[idx] = tj[j].i2;
            mV3[idx] = tj[j].v3;
        }
    }
    __syncthreads();
    if (w < 2 && quad == 0) {
#pragma unroll
        for (int j = 0; j < 4; ++j) {
            const int idx = w * 64 + j * 16 + lane15;
            Top3 tt = tj[j];
            Top3 o; o.v1 = mV1[idx]; o.i1 = mI1[idx]; o.v2 = mV2[idx]; o.i2 = mI2[idx]; o.v3 = mV3[idx];
            top3_merge(tt, o);
            const size_t g = (size_t)cblk * NROWS + n0 + idx;
            pv1[g] = tt.v1; pi1[g] = tt.i1; pv2[g] = tt.v2; pi2[g] = tt.i2; pv3[g] = tt.v3;
        }
    }
}

// Merge 8 splits: decided rows -> output; ambiguous -> listA (candidates) or
// listB (possible hidden candidate / too many).
__global__ void combine_kernel(const float* __restrict__ pv1, const int* __restrict__ pi1,
                               const float* __restrict__ pv2, const int* __restrict__ pi2,
                               const float* __restrict__ pv3,
                               int* __restrict__ fidx, float* __restrict__ outIdx,
                               int* __restrict__ counts,
                               int* __restrict__ listA, int* __restrict__ nA,
                               int* __restrict__ listB, int* __restrict__ nB) {
    const int n = blockIdx.x * blockDim.x + threadIdx.x;
    if (n >= NROWS) return;
    float v1[8], v2[8]; int i1[8], i2[8];
    float b1 = 3.4e38f, v3m = 3.4e38f; int bi = 0x7fffffff;
#pragma unroll
    for (int s = 0; s < 8; ++s) {
        v1[s] = pv1[(size_t)s * NROWS + n]; i1[s] = pi1[(size_t)s * NROWS + n];
        v2[s] = pv2[(size_t)s * NROWS + n]; i2[s] = pi2[(size_t)s * NROWS + n];
        v3m = fminf(v3m, pv3[(size_t)s * NROWS + n]);
        if (v1[s] < b1 || (v1[s] == b1 && i1[s] < bi)) { b1 = v1[s]; bi = i1[s]; }
    }
    if (v3m - b1 < GAP_TAU) {            // a split may hide a 3rd candidate
        const int s = atomicAdd(nB, 1);
        if (s < CAPB) { listB[s] = n; return; }
    } else {
        int ks[16]; int cnt = 0;
#pragma unroll
        for (int s = 0; s < 8; ++s) {
            if (v1[s] - b1 < GAP_TAU) ks[cnt++] = i1[s];
            if (v2[s] - b1 < GAP_TAU) ks[cnt++] = i2[s];
        }
        if (cnt > 1) {
            if (cnt <= 14) {
                const int slot = atomicAdd(nA, 1);
                if (slot < CAPA) {
                    int* e = listA + slot * 16;
                    e[0] = n; e[1] = cnt;
                    for (int c = 0; c < cnt; ++c) e[2 + c] = ks[c];
                    return;
                }
            } else {
                const int s = atomicAdd(nB, 1);
                if (s < CAPB) { listB[s] = n; return; }
            }
        }
    }
    fidx[n] = bi;                        // decided (or cap-overflow fallback)
    outIdx[n] = (float)bi;
    atomicAdd(&counts[bi], 1);
}

// np-exact chain score for each listed candidate; first-min wins.
__global__ __launch_bounds__(256)
void exact_kernel(const float* __restrict__ x, const float* __restrict__ emb,
                  const float* __restrict__ ee, const float* __restrict__ xx,
                  const int* __restrict__ listA, const int* __restrict__ nA,
                  int* __restrict__ fidx, float* __restrict__ outIdx,
                  int* __restrict__ counts) {
    int total = *nA; if (total > CAPA) total = CAPA;
    const int sub = threadIdx.x >> 4;     // 16 entries per block
    const int li  = threadIdx.x & 15;
    for (int e = blockIdx.x * 16 + sub; e < total; e += gridDim.x * 16) {
        const int* ent = listA + (size_t)e * 16;
        const int n = ent[0], cnt = ent[1];
        float s = 3.4e38f; int k = 0x7fffffff;
        if (li < cnt) {
            k = ent[2 + li];
            const int b = n >> 10, p = n & 1023;
            const float* xr = x + (size_t)b * 262144 + p;
            const float* er = emb + (size_t)k * 256;
            float dot = 0.f;
#pragma unroll 8
            for (int d = 0; d < 256; ++d)
                dot = __fmaf_rn(er[d], xr[(size_t)d * 1024], dot);
            s = __fmaf_rn(-2.0f, dot, __fadd_rn(xx[n], ee[k]));
        }
#pragma unroll
        for (int off = 1; off < 16; off <<= 1) {
            const float ov = __shfl_xor(s, off, 16);
            const int   ok = __shfl_xor(k, off, 16);
            if (ov < s || (ov == s && ok < k)) { s = ov; k = ok; }
        }
        if (li == 0) { fidx[n] = k; outIdx[n] = (float)k; atomicAdd(&counts[k], 1); }
    }
}

// np-exact full rescan over all 1024 codes for listB rows (rare).
__global__ __launch_bounds__(256)
void rescanB_kernel(const float* __restrict__ x, const float* __restrict__ emb,
                    const float* __restrict__ ee, const float* __restrict__ xx,
                    const int* __restrict__ listB, const int* __restrict__ nB,
                    int* __restrict__ fidx, float* __restrict__ outIdx,
                    int* __restrict__ counts) {
    __shared__ float xrow[256];
    __shared__ float bV[4];
    __shared__ int   bI[4];
    int total = *nB; if (total > CAPB) total = CAPB;
    for (int wq = blockIdx.x; wq < total; wq += gridDim.x) {
        const int n = listB[wq];
        const int b = n >> 10, p = n & 1023;
        const float* xb = x + (size_t)b * 262144 + p;
        xrow[threadIdx.x] = xb[(size_t)threadIdx.x * 1024];
        __syncthreads();
        const float xxn = xx[n];
        float best = 3.4e38f; int bi = 0x7fffffff;
        for (int k = threadIdx.x; k < 1024; k += 256) {   // ascending k per thread
            const float* e = emb + (size_t)k * 256;
            float dot = 0.f;
            for (int d = 0; d < 256; ++d) dot = __fmaf_rn(e[d], xrow[d], dot);
            const float t1 = __fadd_rn(xxn, ee[k]);
            const float s = __fmaf_rn(-2.0f, dot, t1);
            if (s < best) { best = s; bi = k; }
        }
        for (int off = 32; off > 0; off >>= 1) {
            const float ov = __shfl_down(best, off, 64);
            const int   oi = __shfl_down(bi,   off, 64);
            if (ov < best || (ov == best && oi < bi)) { best = ov; bi = oi; }
        }
        const int lane = threadIdx.x & 63, wv = threadIdx.x >> 6;
        if (lane == 0) { bV[wv] = best; bI[wv] = bi; }
        __syncthreads();
        if (threadIdx.x == 0) {
            float bb = bV[0]; int ii = bI[0];
            for (int i = 1; i < 4; ++i)
                if (bV[i] < bb || (bV[i] == bb && bI[i] < ii)) { bb = bV[i]; ii = bI[i]; }
            fidx[n] = ii;
            outIdx[n] = (float)ii;
            atomicAdd(&counts[ii], 1);
        }
        __syncthreads();
    }
}

// Quantize: one thread = one pixel x 64 consecutive d. Code row read as
// sequential float4 gathers (16 per thread; 4 per 64B line -> each line
// fetched once, L1-hit after). x/out accessed as per-d dwords, coalesced
// across lanes (consecutive lanes = consecutive p). Grid 512 blocks:
// tid>>15 = d-chunk, tid&32767 = pixel.
__global__ __launch_bounds__(256)
void quantize_kernel(const float* __restrict__ x, const float* __restrict__ emb,
                     const int* __restrict__ fidx, float* __restrict__ out,
                     float* __restrict__ sumsq) {
    const int tid = blockIdx.x * 256 + threadIdx.x;   // 0..131071
    const int dchunk = tid >> 15;                     // 0..3
    const int n = tid & 32767;
    const int b = n >> 10, p = n & 1023;
    const int d0 = dchunk * 64;
    const int k = fidx[n];
    const float4* er = (const float4*)(emb + (size_t)k * 256 + d0);   // 16 float4
    const float* xr = x + (size_t)b * 262144 + (size_t)d0 * 1024 + p;
    float* orow = out + (size_t)b * 262144 + (size_t)d0 * 1024 + p;
    float loc = 0.f;
#pragma unroll
    for (int j = 0; j < 16; ++j) {
        const float4 qv = er[j];
        const float q[4] = {qv.x, qv.y, qv.z, qv.w};
#pragma unroll
        for (int i = 0; i < 4; ++i) {
            const size_t off = (size_t)(j * 4 + i) * 1024;
            const float xv = xr[off];
            const float e = q[i] - xv;
            orow[off] = xv + e;           // straight-through: x + (q - x)
            loc = fmaf(e, e, loc);
        }
    }
    for (int off = 32; off > 0; off >>= 1) loc += __shfl_down(loc, off, 64);
    __shared__ float red[4];
    const int lane = threadIdx.x & 63, wv = threadIdx.x >> 6;
    if (lane == 0) red[wv] = loc;
    __syncthreads();
    if (threadIdx.x == 0) atomicAdd(sumsq, red[0] + red[1] + red[2] + red[3]);
}

__global__ void finalize_kernel(const int* __restrict__ counts, const float* __restrict__ sumsq,
                                float* __restrict__ outScalars) {
    const int k = threadIdx.x;
    const float p = (float)counts[k] * (1.0f / 32768.0f);
    float term = p * logf(p + 1e-10f);
    for (int off = 32; off > 0; off >>= 1) term += __shfl_down(term, off, 64);
    __shared__ float red[16];
    const int lane = k & 63, wv = k >> 6;
    if (lane == 0) red[wv] = term;
    __syncthreads();
    if (k == 0) {
        float s = 0.f;
        for (int i = 0; i < 16; ++i) s += red[i];
        const float m = sumsq[0] * (1.0f / 8388608.0f);
        outScalars[0] = 1.25f * m;
        outScalars[1] = expf(-s);
    }
}

extern "C" void kernel_launch(void* const* d_in, const int* in_sizes, int n_in,
                              void* d_out, int out_size, void* d_ws, size_t ws_size,
                              hipStream_t stream) {
    const float* x   = (const float*)d_in[0];
    const float* emb = (const float*)d_in[1];
    float* out = (float*)d_out;
    float* W   = (float*)d_ws;
    float* sumsq = W;
    int*   nA    = (int*)(W + 1);
    int*   nB    = (int*)(W + 2);
    int*   counts = (int*)(W + 64);
    float* ee    = W + 1088;
    float* xx    = W + 2112;
    float* pv1   = W + 34880;
    int*   pi1   = (int*)(W + 297024);
    float* pv2   = W + 559168;
    int*   pi2   = (int*)(W + 821312);
    float* pv3   = W + 1083456;
    int*   listA = (int*)(W + 1345600);
    int*   listB = (int*)(W + 1476672);
    unsigned short* EhW = (unsigned short*)(W + 1484864);
    unsigned short* ElW = (unsigned short*)(W + 1615936);
    int*   fidx  = (int*)(W + 1747008);

    hipMemsetAsync(W, 0, 1088 * sizeof(float), stream);  // sumsq + nA/nB + counts
    prep_kernel<<<388, 256, 0, stream>>>(emb, x, ee, xx, EhW, ElW);
    mfma_argmin_kernel<<<2048, 256, 0, stream>>>(x, EhW, ElW, ee, xx, pv1, pi1, pv2, pi2, pv3);
    combine_kernel<<<128, 256, 0, stream>>>(pv1, pi1, pv2, pi2, pv3, fidx, out + 8388610,
                                            counts, listA, nA, listB, nB);
    exact_kernel<<<256, 256, 0, stream>>>(x, emb, ee, xx, listA, nA, fidx, out + 8388610, counts);
    rescanB_kernel<<<256, 256, 0, stream>>>(x, emb, ee, xx, listB, nB, fidx, out + 8388610, counts);
    quantize_kernel<<<512, 256, 0, stream>>>(x, emb, fidx, out, sumsq);
    finalize_kernel<<<1, 1024, 0, stream>>>(counts, sumsq, out + 8388608);
}

// Round 8
// 233.127 us; speedup vs baseline: 2.1171x; 1.0050x over previous
//
#include <hip/hip_runtime.h>

// VectorQuantizer on MI355X — np-fp32-exact (R4: absmax 0.0). bf16-split MFMA
// approx scores + candidate-exact-compare (np chain) for near-tie rows.
//
// np ref (verified bit-exact): xx/ee = pairwise fp32 sums; dot = d-sequential
// fp32 fma chain; s = fl(fl(xx+ee) - 2*dot); argmin = first minimum.
// Scores sit on a ~3e-5 grid (xx+ee ~ 256-340) -> near-ties pervasive.
//   argmin (MFMA):   per-(row,128-code-split) top-3 values, top-2 indices
//   combine:         global b1; v3-guard -> listB; else known candidates
//                    within TAU: 1 -> decided, <=14 -> listA
//   exact_kernel:    np-exact chain score per candidate (listA)
//   rescanB_kernel:  np-exact full scan (listB, rare)
// R8: X fp32->bf16 h/l split in argmin staging now uses TRUNCATION packed via
// v_perm_b32 (~3 VALU ops/elem vs ~10 for RNE): h = v & 0xFFFF0000 (residual
// exact), l = trunc16(v-h). |dot_err| ~2e-6 << TAU=1e-4; exactness guaranteed
// by the guard+rescue, not the approx rounding mode. (R7 PMC: VALUBusy 42% =
// redundant 8x conversion; LDS conflict counter is inherent b128 8/bank cost,
// padding provably doesn't help - both strides give uniform distribution.)
//
// ws layout (float units):
//   0 sumsq | 1 nA | 2 nB | 64 counts[1024] | 1088 ee[1024] | 2112 xx[32768]
//   34880 pv1 | 297024 pi1 | 559168 pv2 | 821312 pi2 | 1083456 pv3   [8*32768 ea]
//   1345600 listA[16384*16 int] | 1476672 listB[8192 int]
//   1484864 EhW ushort[262144] | 1615936 ElW ushort[262144]
//   1747008 fidx[32768]  -> ~7.1 MB total.

#define NROWS 32768
#define CAPA 16384
#define CAPB 8192
#define GAP_TAU 1e-4f

typedef __attribute__((ext_vector_type(8))) short short8;
typedef __attribute__((ext_vector_type(8))) unsigned short ushort8;
typedef __attribute__((ext_vector_type(4))) float f32x4;
typedef __attribute__((ext_vector_type(4))) unsigned int uint4v;

struct Top3 { float v1, v2, v3; int i1, i2; };

// Merge two sorted top-3s (values sorted asc; indices on slots 1,2).
__device__ __forceinline__ void top3_merge(Top3& a, const Top3& o) {
    Top3 r;
    if (o.v1 < a.v1 || (o.v1 == a.v1 && o.i1 < a.i1)) {
        r.v1 = o.v1; r.i1 = o.i1;
        if (a.v1 < o.v2 || (a.v1 == o.v2 && a.i1 < o.i2)) {
            r.v2 = a.v1; r.i2 = a.i1; r.v3 = fminf(o.v2, a.v2);
        } else {
            r.v2 = o.v2; r.i2 = o.i2; r.v3 = fminf(a.v1, o.v3);
        }
    } else {
        r.v1 = a.v1; r.i1 = a.i1;
        if (o.v1 < a.v2 || (o.v1 == a.v2 && o.i1 < a.i2)) {
            r.v2 = o.v1; r.i2 = o.i1; r.v3 = fminf(a.v2, o.v2);
        } else {
            r.v2 = a.v2; r.i2 = a.i2; r.v3 = fminf(o.v1, a.v3);
        }
    }
    a = r;
}

__device__ __forceinline__ unsigned short bf16_rne(float v) {
    unsigned int u = __float_as_uint(v);
    return (unsigned short)((u + 0x7fffu + ((u >> 16) & 1u)) >> 16);
}
__device__ __forceinline__ float bf16_to_f(unsigned short h) {
    return __uint_as_float(((unsigned int)h) << 16);
}

// numpy pairwise sum of squares over 256: pw128+pw128, 8-lane accumulators.
template <int STRIDE>
__device__ __forceinline__ float np_sumsq256(const float* __restrict__ p) {
    float half[2];
#pragma unroll
    for (int h = 0; h < 2; ++h) {
        float r[8];
#pragma unroll
        for (int j = 0; j < 8; ++j) {
            const float v = p[(size_t)(h * 128 + j) * STRIDE];
            r[j] = __fmul_rn(v, v);
        }
        for (int i = 8; i < 128; i += 8) {
#pragma unroll
            for (int j = 0; j < 8; ++j) {
                const float v = p[(size_t)(h * 128 + i + j) * STRIDE];
                r[j] = __fadd_rn(r[j], __fmul_rn(v, v));
            }
        }
        half[h] = __fadd_rn(__fadd_rn(__fadd_rn(r[0], r[1]), __fadd_rn(r[2], r[3])),
                            __fadd_rn(__fadd_rn(r[4], r[5]), __fadd_rn(r[6], r[7])));
    }
    return __fadd_rn(half[0], half[1]);
}

// blocks 0..3: ee; 4..259: E -> bf16 h/l; 260..387: xx.
__global__ void prep_kernel(const float* __restrict__ emb, const float* __restrict__ x,
                            float* __restrict__ ee, float* __restrict__ xx,
                            unsigned short* __restrict__ EhW, unsigned short* __restrict__ ElW) {
    if (blockIdx.x < 4) {
        const int k = blockIdx.x * 256 + threadIdx.x;
        ee[k] = np_sumsq256<1>(emb + (size_t)k * 256);
        return;
    }
    if (blockIdx.x >= 260) {
        const int n = (blockIdx.x - 260) * 256 + threadIdx.x;
        const int b = n >> 10, p = n & 1023;
        xx[n] = np_sumsq256<1024>(x + (size_t)b * 262144 + p);
        return;
    }
    const int eid = (blockIdx.x - 4) * 256 + threadIdx.x;   // 0..65535
    const int base = eid * 4;
    float4 v = *(const float4*)(emb + base);
    const float vv[4] = {v.x, v.y, v.z, v.w};
    unsigned short h[4], l[4];
#pragma unroll
    for (int i = 0; i < 4; ++i) {
        h[i] = bf16_rne(vv[i]);
        l[i] = bf16_rne(vv[i] - bf16_to_f(h[i]));
    }
    *(ushort4*)(EhW + base) = make_ushort4(h[0], h[1], h[2], h[3]);
    *(ushort4*)(ElW + base) = make_ushort4(l[0], l[1], l[2], l[3]);
}

// MFMA argmin: 128 codes x 128 rows per block; grid 2048 = 256 n-blocks x 8
// code-splits. 4 waves: w>>1 code-half, w&1 n-half; 4x4 tiles of 16x16x32.
// Epilogue: per-row top-3 values + top-2 indices within the split.
__global__ __launch_bounds__(256, 2)
void mfma_argmin_kernel(const float* __restrict__ x,
                        const unsigned short* __restrict__ EhW, const unsigned short* __restrict__ ElW,
                        const float* __restrict__ ee, const float* __restrict__ xx,
                        float* __restrict__ pv1, int* __restrict__ pi1,
                        float* __restrict__ pv2, int* __restrict__ pi2,
                        float* __restrict__ pv3) {
    __shared__ unsigned short Eh_s[128 * 32];  // [code][k], 64B rows
    __shared__ unsigned short El_s[128 * 32];
    __shared__ unsigned short Xh_s[128 * 32];  // [n][k]
    __shared__ unsigned short Xl_s[128 * 32];
    __shared__ float eeLds[128];
    __shared__ float mV1[128], mV2[128], mV3[128];
    __shared__ int   mI1[128], mI2[128];

    const int t = threadIdx.x;
    const int w = t >> 6, lane = t & 63;
    const int lane15 = lane & 15, quad = lane >> 4;
    const int nblk = blockIdx.x >> 3, cblk = blockIdx.x & 7;
    const int n0 = nblk * 128, c0 = cblk * 128;
    const int b = n0 >> 10, p0 = n0 & 1023;           // 128 | 1024
    const float* xb = x + (size_t)b * 262144 + p0;    // + d*1024 + p

    if (t < 128) eeLds[t] = ee[c0 + t];

    f32x4 acc[4][4];
#pragma unroll
    for (int i = 0; i < 4; ++i)
#pragma unroll
        for (int j = 0; j < 4; ++j) acc[i][j] = (f32x4){0.f, 0.f, 0.f, 0.f};

    for (int dc = 0; dc < 8; ++dc) {
        const int d0 = dc * 32;
        __syncthreads();
        // X tile: load 8 strided fp32, truncation-split packed via v_perm:
        // h = v & 0xFFFF0000 (residual exact), l = trunc16(v - h).
#pragma unroll
        for (int iter = 0; iter < 2; ++iter) {
            const int id = iter * 256 + t;
            const int p = id & 127, dblk = id >> 7;
            const float* src = xb + (size_t)(d0 + dblk * 8) * 1024 + p;
            float v[8];
#pragma unroll
            for (int j = 0; j < 8; ++j) v[j] = src[(size_t)j * 1024];
            uint4v uh, ul;
#pragma unroll
            for (int jj = 0; jj < 4; ++jj) {
                const unsigned int u0 = __float_as_uint(v[2 * jj]);
                const unsigned int u1 = __float_as_uint(v[2 * jj + 1]);
                uh[jj] = __builtin_amdgcn_perm(u1, u0, 0x07060302u);
                const float r0 = v[2 * jj]     - __uint_as_float(u0 & 0xFFFF0000u);
                const float r1 = v[2 * jj + 1] - __uint_as_float(u1 & 0xFFFF0000u);
                ul[jj] = __builtin_amdgcn_perm(__float_as_uint(r1), __float_as_uint(r0), 0x07060302u);
            }
            *(uint4v*)&Xh_s[p * 32 + dblk * 8] = uh;
            *(uint4v*)&Xl_s[p * 32 + dblk * 8] = ul;
        }
        // E tile: copy bf16 h/l. row = id>>2, 16B col = id&3.
#pragma unroll
        for (int iter = 0; iter < 2; ++iter) {
            const int id = iter * 256 + t;
            const int row = id >> 2, col = id & 3;
            const size_t g = (size_t)(c0 + row) * 256 + d0 + col * 8;
            *(ushort8*)&Eh_s[row * 32 + col * 8] = *(const ushort8*)(EhW + g);
            *(ushort8*)&El_s[row * 32 + col * 8] = *(const ushort8*)(ElW + g);
        }
        __syncthreads();
        short8 ah[4], al[4], bhf[4], blf[4];
#pragma unroll
        for (int i = 0; i < 4; ++i) {
            const int cr = (w >> 1) * 64 + i * 16 + lane15;
            ah[i] = *(const short8*)&Eh_s[cr * 32 + quad * 8];
            al[i] = *(const short8*)&El_s[cr * 32 + quad * 8];
        }
#pragma unroll
        for (int j = 0; j < 4; ++j) {
            const int nr = (w & 1) * 64 + j * 16 + lane15;
            bhf[j] = *(const short8*)&Xh_s[nr * 32 + quad * 8];
            blf[j] = *(const short8*)&Xl_s[nr * 32 + quad * 8];
        }
#pragma unroll
        for (int i = 0; i < 4; ++i)
#pragma unroll
            for (int j = 0; j < 4; ++j) {
                acc[i][j] = __builtin_amdgcn_mfma_f32_16x16x32_bf16(al[i], bhf[j], acc[i][j], 0, 0, 0);
                acc[i][j] = __builtin_amdgcn_mfma_f32_16x16x32_bf16(ah[i], blf[j], acc[i][j], 0, 0, 0);
                acc[i][j] = __builtin_amdgcn_mfma_f32_16x16x32_bf16(ah[i], bhf[j], acc[i][j], 0, 0, 0);
            }
    }
    // Epilogue: per-n top-3 over this block's 128 codes.
    // C layout (16x16): col=lane&15 -> n, row=quad*4+reg -> code.
    Top3 tj[4];
#pragma unroll
    for (int j = 0; j < 4; ++j) {
        const float xxv = xx[n0 + (w & 1) * 64 + j * 16 + lane15];
        Top3 tt; tt.v1 = tt.v2 = tt.v3 = 3.4e38f; tt.i1 = tt.i2 = 0x7fffffff;
#pragma unroll
        for (int i = 0; i < 4; ++i)
#pragma unroll
            for (int r = 0; r < 4; ++r) {
                const int cl = (w >> 1) * 64 + i * 16 + quad * 4 + r;
                const float t1 = __fadd_rn(xxv, eeLds[cl]);
                const float s = __fmaf_rn(-2.0f, acc[i][j][r], t1);
                const int kk = c0 + cl;
                if (s < tt.v1) { tt.v3 = tt.v2; tt.v2 = tt.v1; tt.i2 = tt.i1; tt.v1 = s; tt.i1 = kk; }
                else if (s < tt.v2) { tt.v3 = tt.v2; tt.v2 = s; tt.i2 = kk; }
                else if (s < tt.v3) { tt.v3 = s; }
            }
#pragma unroll
        for (int off = 16; off <= 32; off <<= 1) {   // merge quads
            Top3 o;
            o.v1 = __shfl_xor(tt.v1, off, 64); o.i1 = __shfl_xor(tt.i1, off, 64);
            o.v2 = __shfl_xor(tt.v2, off, 64); o.i2 = __shfl_xor(tt.i2, off, 64);
            o.v3 = __shfl_xor(tt.v3, off, 64);
            top3_merge(tt, o);
        }
        tj[j] = tt;
    }
    __syncthreads();
    if (w >= 2 && quad == 0) {
#pragma unroll
        for (int j = 0; j < 4; ++j) {
            const int idx = (w & 1) * 64 + j * 16 + lane15;
            mV1[idx] = tj[j].v1; mI1[idx] = tj[j].i1;
            mV2[idx] = tj[j].v2; mI2[idx] = tj[j].i2;
            mV3[idx] = tj[j].v3;
        }
    }
    __syncthreads();
    if (w < 2 && quad == 0) {
#pragma unroll
        for (int j = 0; j < 4; ++j) {
            const int idx = w * 64 + j * 16 + lane15;
            Top3 tt = tj[j];
            Top3 o; o.v1 = mV1[idx]; o.i1 = mI1[idx]; o.v2 = mV2[idx]; o.i2 = mI2[idx]; o.v3 = mV3[idx];
            top3_merge(tt, o);
            const size_t g = (size_t)cblk * NROWS + n0 + idx;
            pv1[g] = tt.v1; pi1[g] = tt.i1; pv2[g] = tt.v2; pi2[g] = tt.i2; pv3[g] = tt.v3;
        }
    }
}

// Merge 8 splits: decided rows -> output; ambiguous -> listA (candidates) or
// listB (possible hidden candidate / too many).
__global__ void combine_kernel(const float* __restrict__ pv1, const int* __restrict__ pi1,
                               const float* __restrict__ pv2, const int* __restrict__ pi2,
                               const float* __restrict__ pv3,
                               int* __restrict__ fidx, float* __restrict__ outIdx,
                               int* __restrict__ counts,
                               int* __restrict__ listA, int* __restrict__ nA,
                               int* __restrict__ listB, int* __restrict__ nB) {
    const int n = blockIdx.x * blockDim.x + threadIdx.x;
    if (n >= NROWS) return;
    float v1[8], v2[8]; int i1[8], i2[8];
    float b1 = 3.4e38f, v3m = 3.4e38f; int bi = 0x7fffffff;
#pragma unroll
    for (int s = 0; s < 8; ++s) {
        v1[s] = pv1[(size_t)s * NROWS + n]; i1[s] = pi1[(size_t)s * NROWS + n];
        v2[s] = pv2[(size_t)s * NROWS + n]; i2[s] = pi2[(size_t)s * NROWS + n];
        v3m = fminf(v3m, pv3[(size_t)s * NROWS + n]);
        if (v1[s] < b1 || (v1[s] == b1 && i1[s] < bi)) { b1 = v1[s]; bi = i1[s]; }
    }
    if (v3m - b1 < GAP_TAU) {            // a split may hide a 3rd candidate
        const int s = atomicAdd(nB, 1);
        if (s < CAPB) { listB[s] = n; return; }
    } else {
        int ks[16]; int cnt = 0;
#pragma unroll
        for (int s = 0; s < 8; ++s) {
            if (v1[s] - b1 < GAP_TAU) ks[cnt++] = i1[s];
            if (v2[s] - b1 < GAP_TAU) ks[cnt++] = i2[s];
        }
        if (cnt > 1) {
            if (cnt <= 14) {
                const int slot = atomicAdd(nA, 1);
                if (slot < CAPA) {
                    int* e = listA + slot * 16;
                    e[0] = n; e[1] = cnt;
                    for (int c = 0; c < cnt; ++c) e[2 + c] = ks[c];
                    return;
                }
            } else {
                const int s = atomicAdd(nB, 1);
                if (s < CAPB) { listB[s] = n; return; }
            }
        }
    }
    fidx[n] = bi;                        // decided (or cap-overflow fallback)
    outIdx[n] = (float)bi;
    atomicAdd(&counts[bi], 1);
}

// np-exact chain score for each listed candidate; first-min wins.
__global__ __launch_bounds__(256)
void exact_kernel(const float* __restrict__ x, const float* __restrict__ emb,
                  const float* __restrict__ ee, const float* __restrict__ xx,
                  const int* __restrict__ listA, const int* __restrict__ nA,
                  int* __restrict__ fidx, float* __restrict__ outIdx,
                  int* __restrict__ counts) {
    int total = *nA; if (total > CAPA) total = CAPA;
    const int sub = threadIdx.x >> 4;     // 16 entries per block
    const int li  = threadIdx.x & 15;
    for (int e = blockIdx.x * 16 + sub; e < total; e += gridDim.x * 16) {
        const int* ent = listA + (size_t)e * 16;
        const int n = ent[0], cnt = ent[1];
        float s = 3.4e38f; int k = 0x7fffffff;
        if (li < cnt) {
            k = ent[2 + li];
            const int b = n >> 10, p = n & 1023;
            const float* xr = x + (size_t)b * 262144 + p;
            const float* er = emb + (size_t)k * 256;
            float dot = 0.f;
#pragma unroll 8
            for (int d = 0; d < 256; ++d)
                dot = __fmaf_rn(er[d], xr[(size_t)d * 1024], dot);
            s = __fmaf_rn(-2.0f, dot, __fadd_rn(xx[n], ee[k]));
        }
#pragma unroll
        for (int off = 1; off < 16; off <<= 1) {
            const float ov = __shfl_xor(s, off, 16);
            const int   ok = __shfl_xor(k, off, 16);
            if (ov < s || (ov == s && ok < k)) { s = ov; k = ok; }
        }
        if (li == 0) { fidx[n] = k; outIdx[n] = (float)k; atomicAdd(&counts[k], 1); }
    }
}

// np-exact full rescan over all 1024 codes for listB rows (rare).
__global__ __launch_bounds__(256)
void rescanB_kernel(const float* __restrict__ x, const float* __restrict__ emb,
                    const float* __restrict__ ee, const float* __restrict__ xx,
                    const int* __restrict__ listB, const int* __restrict__ nB,
                    int* __restrict__ fidx, float* __restrict__ outIdx,
                    int* __restrict__ counts) {
    __shared__ float xrow[256];
    __shared__ float bV[4];
    __shared__ int   bI[4];
    int total = *nB; if (total > CAPB) total = CAPB;
    for (int wq = blockIdx.x; wq < total; wq += gridDim.x) {
        const int n = listB[wq];
        const int b = n >> 10, p = n & 1023;
        const float* xb = x + (size_t)b * 262144 + p;
        xrow[threadIdx.x] = xb[(size_t)threadIdx.x * 1024];
        __syncthreads();
        const float xxn = xx[n];
        float best = 3.4e38f; int bi = 0x7fffffff;
        for (int k = threadIdx.x; k < 1024; k += 256) {   // ascending k per thread
            const float* e = emb + (size_t)k * 256;
            float dot = 0.f;
            for (int d = 0; d < 256; ++d) dot = __fmaf_rn(e[d], xrow[d], dot);
            const float t1 = __fadd_rn(xxn, ee[k]);
            const float s = __fmaf_rn(-2.0f, dot, t1);
            if (s < best) { best = s; bi = k; }
        }
        for (int off = 32; off > 0; off >>= 1) {
            const float ov = __shfl_down(best, off, 64);
            const int   oi = __shfl_down(bi,   off, 64);
            if (ov < best || (ov == best && oi < bi)) { best = ov; bi = oi; }
        }
        const int lane = threadIdx.x & 63, wv = threadIdx.x >> 6;
        if (lane == 0) { bV[wv] = best; bI[wv] = bi; }
        __syncthreads();
        if (threadIdx.x == 0) {
            float bb = bV[0]; int ii = bI[0];
            for (int i = 1; i < 4; ++i)
                if (bV[i] < bb || (bV[i] == bb && bI[i] < ii)) { bb = bV[i]; ii = bI[i]; }
            fidx[n] = ii;
            outIdx[n] = (float)ii;
            atomicAdd(&counts[ii], 1);
        }
        __syncthreads();
    }
}

// Quantize: one thread = one pixel x 64 consecutive d. Code row read as
// sequential float4 gathers (each 64B line fetched once); x/out per-d dwords
// coalesced across lanes. tid>>15 = d-chunk, tid&32767 = pixel.
__global__ __launch_bounds__(256)
void quantize_kernel(const float* __restrict__ x, const float* __restrict__ emb,
                     const int* __restrict__ fidx, float* __restrict__ out,
                     float* __restrict__ sumsq) {
    const int tid = blockIdx.x * 256 + threadIdx.x;   // 0..131071
    const int dchunk = tid >> 15;                     // 0..3
    const int n = tid & 32767;
    const int b = n >> 10, p = n & 1023;
    const int d0 = dchunk * 64;
    const int k = fidx[n];
    const float4* er = (const float4*)(emb + (size_t)k * 256 + d0);   // 16 float4
    const float* xr = x + (size_t)b * 262144 + (size_t)d0 * 1024 + p;
    float* orow = out + (size_t)b * 262144 + (size_t)d0 * 1024 + p;
    float loc = 0.f;
#pragma unroll
    for (int j = 0; j < 16; ++j) {
        const float4 qv = er[j];
        const float q[4] = {qv.x, qv.y, qv.z, qv.w};
#pragma unroll
        for (int i = 0; i < 4; ++i) {
            const size_t off = (size_t)(j * 4 + i) * 1024;
            const float xv = xr[off];
            const float e = q[i] - xv;
            orow[off] = xv + e;           // straight-through: x + (q - x)
            loc = fmaf(e, e, loc);
        }
    }
    for (int off = 32; off > 0; off >>= 1) loc += __shfl_down(loc, off, 64);
    __shared__ float red[4];
    const int lane = threadIdx.x & 63, wv = threadIdx.x >> 6;
    if (lane == 0) red[wv] = loc;
    __syncthreads();
    if (threadIdx.x == 0) atomicAdd(sumsq, red[0] + red[1] + red[2] + red[3]);
}

__global__ void finalize_kernel(const int* __restrict__ counts, const float* __restrict__ sumsq,
                                float* __restrict__ outScalars) {
    const int k = threadIdx.x;
    const float p = (float)counts[k] * (1.0f / 32768.0f);
    float term = p * logf(p + 1e-10f);
    for (int off = 32; off > 0; off >>= 1) term += __shfl_down(term, off, 64);
    __shared__ float red[16];
    const int lane = k & 63, wv = k >> 6;
    if (lane == 0) red[wv] = term;
    __syncthreads();
    if (k == 0) {
        float s = 0.f;
        for (int i = 0; i < 16; ++i) s += red[i];
        const float m = sumsq[0] * (1.0f / 8388608.0f);
        outScalars[0] = 1.25f * m;
        outScalars[1] = expf(-s);
    }
}

extern "C" void kernel_launch(void* const* d_in, const int* in_sizes, int n_in,
                              void* d_out, int out_size, void* d_ws, size_t ws_size,
                              hipStream_t stream) {
    const float* x   = (const float*)d_in[0];
    const float* emb = (const float*)d_in[1];
    float* out = (float*)d_out;
    float* W   = (float*)d_ws;
    float* sumsq = W;
    int*   nA    = (int*)(W + 1);
    int*   nB    = (int*)(W + 2);
    int*   counts = (int*)(W + 64);
    float* ee    = W + 1088;
    float* xx    = W + 2112;
    float* pv1   = W + 34880;
    int*   pi1   = (int*)(W + 297024);
    float* pv2   = W + 559168;
    int*   pi2   = (int*)(W + 821312);
    float* pv3   = W + 1083456;
    int*   listA = (int*)(W + 1345600);
    int*   listB = (int*)(W + 1476672);
    unsigned short* EhW = (unsigned short*)(W + 1484864);
    unsigned short* ElW = (unsigned short*)(W + 1615936);
    int*   fidx  = (int*)(W + 1747008);

    hipMemsetAsync(W, 0, 1088 * sizeof(float), stream);  // sumsq + nA/nB + counts
    prep_kernel<<<388, 256, 0, stream>>>(emb, x, ee, xx, EhW, ElW);
    mfma_argmin_kernel<<<2048, 256, 0, stream>>>(x, EhW, ElW, ee, xx, pv1, pi1, pv2, pi2, pv3);
    combine_kernel<<<128, 256, 0, stream>>>(pv1, pi1, pv2, pi2, pv3, fidx, out + 8388610,
                                            counts, listA, nA, listB, nB);
    exact_kernel<<<256, 256, 0, stream>>>(x, emb, ee, xx, listA, nA, fidx, out + 8388610, counts);
    rescanB_kernel<<<256, 256, 0, stream>>>(x, emb, ee, xx, listB, nB, fidx, out + 8388610, counts);
    quantize_kernel<<<512, 256, 0, stream>>>(x, emb, fidx, out, sumsq);
    finalize_kernel<<<1, 1024, 0, stream>>>(counts, sumsq, out + 8388608);
}

// Round 9
// 230.900 us; speedup vs baseline: 2.1375x; 1.0096x over previous
//
#include <hip/hip_runtime.h>

// VectorQuantizer on MI355X — np-fp32-exact (R4: absmax 0.0). bf16-split MFMA
// approx scores + candidate-exact-compare (np chain) for near-tie rows.
//
// np ref (verified bit-exact): xx/ee = pairwise fp32 sums; dot = d-sequential
// fp32 fma chain; s = fl(fl(xx+ee) - 2*dot); argmin = first minimum.
// Scores sit on a ~3e-5 grid -> near-ties pervasive. Decision architecture:
//   argmin (MFMA): per-(row,128-code-split) top-4 VALUES + top-3 INDICES
//                  (value-only ordering: tie order irrelevant, any within-TAU
//                  ambiguity is resolved by exact compare downstream)
//   combine:       b1 = global best; if any split's v4 within TAU of b1 ->
//                  listB (hidden candidate possible; ~never). Else collect all
//                  recorded (v,i) with v-b1<TAU (<=24): 1 -> decided, else listA
//   exact_kernel:  np-exact chain score per candidate, 32 lanes/entry
//   rescanB:       np-exact full scan (safety net)
// R9: argmin decode swapped (nblk=b&255, cblk=b>>8) so the 8 code-split
// siblings of an X row-tile land on the SAME XCD (256 = 0 mod 8 round-robin)
// -> X tile HBM-fetched once, L2-served 7x (R8 FETCH=133MB was 8 XCDs each
// fetching every tile). launch_bounds(256,4) -> 4 blocks/CU for latency hiding.
//
// ws layout (float units):
//   0 sumsq | 1 nA | 2 nB | 64 counts[1024] | 1088 ee[1024] | 2112 xx[32768]
//   34880 pv0 | 297024 pv1 | 559168 pv2 | 821312 pv3            [8*32768 ea]
//   1083456 pi0 | 1345600 pi1 | 1607744 pi2                     [8*32768 ea]
//   1869888 listA[16384*32 int] | 2394176 listB[8192 int]
//   2402368 EhW ushort[262144] | 2533440 ElW ushort[262144]
//   2664512 fidx[32768] -> ~10.8 MB total.

#define NROWS 32768
#define CAPA 16384
#define CAPB 8192
#define GAP_TAU 1e-4f

typedef __attribute__((ext_vector_type(8))) short short8;
typedef __attribute__((ext_vector_type(8))) unsigned short ushort8;
typedef __attribute__((ext_vector_type(4))) float f32x4;
typedef __attribute__((ext_vector_type(4))) unsigned int uint4v;

// Top-4 values, top-3 indices, value-sorted ascending.
struct Top4 { float v0, v1, v2, v3; int i0, i1, i2; };

__device__ __forceinline__ void top4_init(Top4& t) {
    t.v0 = t.v1 = t.v2 = t.v3 = 3.4e38f;
    t.i0 = t.i1 = t.i2 = 0x7fffffff;
}
__device__ __forceinline__ void top4_insert(Top4& t, float cv, int ci) {
    if (cv < t.v3) {
        if (cv < t.v2) {
            t.v3 = t.v2;
            if (cv < t.v1) {
                t.v2 = t.v1; t.i2 = t.i1;
                if (cv < t.v0) { t.v1 = t.v0; t.i1 = t.i0; t.v0 = cv; t.i0 = ci; }
                else           { t.v1 = cv; t.i1 = ci; }
            } else { t.v2 = cv; t.i2 = ci; }
        } else { t.v3 = cv; }
    }
}
__device__ __forceinline__ void top4_merge(Top4& t, const Top4& o) {
    top4_insert(t, o.v0, o.i0);
    top4_insert(t, o.v1, o.i1);
    top4_insert(t, o.v2, o.i2);
    t.v3 = fminf(t.v3, o.v3);
}

__device__ __forceinline__ unsigned short bf16_rne(float v) {
    unsigned int u = __float_as_uint(v);
    return (unsigned short)((u + 0x7fffu + ((u >> 16) & 1u)) >> 16);
}
__device__ __forceinline__ float bf16_to_f(unsigned short h) {
    return __uint_as_float(((unsigned int)h) << 16);
}

// numpy pairwise sum of squares over 256: pw128+pw128, 8-lane accumulators.
template <int STRIDE>
__device__ __forceinline__ float np_sumsq256(const float* __restrict__ p) {
    float half[2];
#pragma unroll
    for (int h = 0; h < 2; ++h) {
        float r[8];
#pragma unroll
        for (int j = 0; j < 8; ++j) {
            const float v = p[(size_t)(h * 128 + j) * STRIDE];
            r[j] = __fmul_rn(v, v);
        }
        for (int i = 8; i < 128; i += 8) {
#pragma unroll
            for (int j = 0; j < 8; ++j) {
                const float v = p[(size_t)(h * 128 + i + j) * STRIDE];
                r[j] = __fadd_rn(r[j], __fmul_rn(v, v));
            }
        }
        half[h] = __fadd_rn(__fadd_rn(__fadd_rn(r[0], r[1]), __fadd_rn(r[2], r[3])),
                            __fadd_rn(__fadd_rn(r[4], r[5]), __fadd_rn(r[6], r[7])));
    }
    return __fadd_rn(half[0], half[1]);
}

// blocks 0..3: ee; 4..259: E -> bf16 h/l; 260..387: xx.
__global__ void prep_kernel(const float* __restrict__ emb, const float* __restrict__ x,
                            float* __restrict__ ee, float* __restrict__ xx,
                            unsigned short* __restrict__ EhW, unsigned short* __restrict__ ElW) {
    if (blockIdx.x < 4) {
        const int k = blockIdx.x * 256 + threadIdx.x;
        ee[k] = np_sumsq256<1>(emb + (size_t)k * 256);
        return;
    }
    if (blockIdx.x >= 260) {
        const int n = (blockIdx.x - 260) * 256 + threadIdx.x;
        const int b = n >> 10, p = n & 1023;
        xx[n] = np_sumsq256<1024>(x + (size_t)b * 262144 + p);
        return;
    }
    const int eid = (blockIdx.x - 4) * 256 + threadIdx.x;   // 0..65535
    const int base = eid * 4;
    float4 v = *(const float4*)(emb + base);
    const float vv[4] = {v.x, v.y, v.z, v.w};
    unsigned short h[4], l[4];
#pragma unroll
    for (int i = 0; i < 4; ++i) {
        h[i] = bf16_rne(vv[i]);
        l[i] = bf16_rne(vv[i] - bf16_to_f(h[i]));
    }
    *(ushort4*)(EhW + base) = make_ushort4(h[0], h[1], h[2], h[3]);
    *(ushort4*)(ElW + base) = make_ushort4(l[0], l[1], l[2], l[3]);
}

// MFMA argmin: 128 codes x 128 rows per block; grid 2048.
// Decode: nblk = b & 255 (fast), cblk = b >> 8 -> the 8 siblings of a row-tile
// are 256 apart => same XCD (round-robin %8) => X tile shared via that L2.
// 4 waves: w>>1 code-half, w&1 n-half; 4x4 tiles of 16x16x32.
__global__ __launch_bounds__(256, 4)
void mfma_argmin_kernel(const float* __restrict__ x,
                        const unsigned short* __restrict__ EhW, const unsigned short* __restrict__ ElW,
                        const float* __restrict__ ee, const float* __restrict__ xx,
                        float* __restrict__ pv0, float* __restrict__ pv1,
                        float* __restrict__ pv2, float* __restrict__ pv3,
                        int* __restrict__ pi0, int* __restrict__ pi1, int* __restrict__ pi2) {
    __shared__ unsigned short Eh_s[128 * 32];  // [code][k], 64B rows
    __shared__ unsigned short El_s[128 * 32];
    __shared__ unsigned short Xh_s[128 * 32];  // [n][k]
    __shared__ unsigned short Xl_s[128 * 32];
    __shared__ float eeLds[128];
    __shared__ float mV0[128], mV1[128], mV2[128], mV3[128];
    __shared__ int   mI0[128], mI1[128], mI2[128];

    const int t = threadIdx.x;
    const int w = t >> 6, lane = t & 63;
    const int lane15 = lane & 15, quad = lane >> 4;
    const int nblk = blockIdx.x & 255, cblk = blockIdx.x >> 8;
    const int n0 = nblk * 128, c0 = cblk * 128;
    const int b = n0 >> 10, p0 = n0 & 1023;           // 128 | 1024
    const float* xb = x + (size_t)b * 262144 + p0;    // + d*1024 + p

    if (t < 128) eeLds[t] = ee[c0 + t];

    f32x4 acc[4][4];
#pragma unroll
    for (int i = 0; i < 4; ++i)
#pragma unroll
        for (int j = 0; j < 4; ++j) acc[i][j] = (f32x4){0.f, 0.f, 0.f, 0.f};

    for (int dc = 0; dc < 8; ++dc) {
        const int d0 = dc * 32;
        __syncthreads();
        // X tile: load 8 strided fp32, truncation-split packed via v_perm:
        // h = v & 0xFFFF0000 (residual exact), l = trunc16(v - h).
#pragma unroll
        for (int iter = 0; iter < 2; ++iter) {
            const int id = iter * 256 + t;
            const int p = id & 127, dblk = id >> 7;
            const float* src = xb + (size_t)(d0 + dblk * 8) * 1024 + p;
            float v[8];
#pragma unroll
            for (int j = 0; j < 8; ++j) v[j] = src[(size_t)j * 1024];
            uint4v uh, ul;
#pragma unroll
            for (int jj = 0; jj < 4; ++jj) {
                const unsigned int u0 = __float_as_uint(v[2 * jj]);
                const unsigned int u1 = __float_as_uint(v[2 * jj + 1]);
                uh[jj] = __builtin_amdgcn_perm(u1, u0, 0x07060302u);
                const float r0 = v[2 * jj]     - __uint_as_float(u0 & 0xFFFF0000u);
                const float r1 = v[2 * jj + 1] - __uint_as_float(u1 & 0xFFFF0000u);
                ul[jj] = __builtin_amdgcn_perm(__float_as_uint(r1), __float_as_uint(r0), 0x07060302u);
            }
            *(uint4v*)&Xh_s[p * 32 + dblk * 8] = uh;
            *(uint4v*)&Xl_s[p * 32 + dblk * 8] = ul;
        }
        // E tile: copy bf16 h/l. row = id>>2, 16B col = id&3.
#pragma unroll
        for (int iter = 0; iter < 2; ++iter) {
            const int id = iter * 256 + t;
            const int row = id >> 2, col = id & 3;
            const size_t g = (size_t)(c0 + row) * 256 + d0 + col * 8;
            *(ushort8*)&Eh_s[row * 32 + col * 8] = *(const ushort8*)(EhW + g);
            *(ushort8*)&El_s[row * 32 + col * 8] = *(const ushort8*)(ElW + g);
        }
        __syncthreads();
        short8 ah[4], al[4], bhf[4], blf[4];
#pragma unroll
        for (int i = 0; i < 4; ++i) {
            const int cr = (w >> 1) * 64 + i * 16 + lane15;
            ah[i] = *(const short8*)&Eh_s[cr * 32 + quad * 8];
            al[i] = *(const short8*)&El_s[cr * 32 + quad * 8];
        }
#pragma unroll
        for (int j = 0; j < 4; ++j) {
            const int nr = (w & 1) * 64 + j * 16 + lane15;
            bhf[j] = *(const short8*)&Xh_s[nr * 32 + quad * 8];
            blf[j] = *(const short8*)&Xl_s[nr * 32 + quad * 8];
        }
#pragma unroll
        for (int i = 0; i < 4; ++i)
#pragma unroll
            for (int j = 0; j < 4; ++j) {
                acc[i][j] = __builtin_amdgcn_mfma_f32_16x16x32_bf16(al[i], bhf[j], acc[i][j], 0, 0, 0);
                acc[i][j] = __builtin_amdgcn_mfma_f32_16x16x32_bf16(ah[i], blf[j], acc[i][j], 0, 0, 0);
                acc[i][j] = __builtin_amdgcn_mfma_f32_16x16x32_bf16(ah[i], bhf[j], acc[i][j], 0, 0, 0);
            }
    }
    // Epilogue: per-n top-4 over this block's 128 codes.
    // C layout (16x16): col=lane&15 -> n, row=quad*4+reg -> code.
    Top4 tj[4];
#pragma unroll
    for (int j = 0; j < 4; ++j) {
        const float xxv = xx[n0 + (w & 1) * 64 + j * 16 + lane15];
        Top4 tt; top4_init(tt);
#pragma unroll
        for (int i = 0; i < 4; ++i)
#pragma unroll
            for (int r = 0; r < 4; ++r) {
                const int cl = (w >> 1) * 64 + i * 16 + quad * 4 + r;
                const float t1 = __fadd_rn(xxv, eeLds[cl]);
                const float s = __fmaf_rn(-2.0f, acc[i][j][r], t1);
                top4_insert(tt, s, c0 + cl);
            }
#pragma unroll
        for (int off = 16; off <= 32; off <<= 1) {   // merge quads
            Top4 o;
            o.v0 = __shfl_xor(tt.v0, off, 64); o.i0 = __shfl_xor(tt.i0, off, 64);
            o.v1 = __shfl_xor(tt.v1, off, 64); o.i1 = __shfl_xor(tt.i1, off, 64);
            o.v2 = __shfl_xor(tt.v2, off, 64); o.i2 = __shfl_xor(tt.i2, off, 64);
            o.v3 = __shfl_xor(tt.v3, off, 64);
            top4_merge(tt, o);
        }
        tj[j] = tt;
    }
    __syncthreads();
    if (w >= 2 && quad == 0) {
#pragma unroll
        for (int j = 0; j < 4; ++j) {
            const int idx = (w & 1) * 64 + j * 16 + lane15;
            mV0[idx] = tj[j].v0; mV1[idx] = tj[j].v1; mV2[idx] = tj[j].v2; mV3[idx] = tj[j].v3;
            mI0[idx] = tj[j].i0; mI1[idx] = tj[j].i1; mI2[idx] = tj[j].i2;
        }
    }
    __syncthreads();
    if (w < 2 && quad == 0) {
#pragma unroll
        for (int j = 0; j < 4; ++j) {
            const int idx = w * 64 + j * 16 + lane15;
            Top4 tt = tj[j];
            Top4 o;
            o.v0 = mV0[idx]; o.v1 = mV1[idx]; o.v2 = mV2[idx]; o.v3 = mV3[idx];
            o.i0 = mI0[idx]; o.i1 = mI1[idx]; o.i2 = mI2[idx];
            top4_merge(tt, o);
            const size_t g = (size_t)cblk * NROWS + n0 + idx;
            pv0[g] = tt.v0; pv1[g] = tt.v1; pv2[g] = tt.v2; pv3[g] = tt.v3;
            pi0[g] = tt.i0; pi1[g] = tt.i1; pi2[g] = tt.i2;
        }
    }
}

// Merge 8 splits: decided rows -> output; ambiguous -> listA (<=24 candidates)
// or listB (a split's v4 within TAU of b1 -> hidden candidate possible).
__global__ void combine_kernel(const float* __restrict__ pv0, const float* __restrict__ pv1,
                               const float* __restrict__ pv2, const float* __restrict__ pv3,
                               const int* __restrict__ pi0, const int* __restrict__ pi1,
                               const int* __restrict__ pi2,
                               int* __restrict__ fidx, float* __restrict__ outIdx,
                               int* __restrict__ counts,
                               int* __restrict__ listA, int* __restrict__ nA,
                               int* __restrict__ listB, int* __restrict__ nB) {
    const int n = blockIdx.x * blockDim.x + threadIdx.x;
    if (n >= NROWS) return;
    float v0[8], v1[8], v2[8]; int i0[8], i1[8], i2[8];
    float b1 = 3.4e38f, v4m = 3.4e38f;
#pragma unroll
    for (int s = 0; s < 8; ++s) {
        const size_t g = (size_t)s * NROWS + n;
        v0[s] = pv0[g]; v1[s] = pv1[g]; v2[s] = pv2[g];
        i0[s] = pi0[g]; i1[s] = pi1[g]; i2[s] = pi2[g];
        b1 = fminf(b1, v0[s]);
        v4m = fminf(v4m, pv3[g]);
    }
    if (v4m - b1 < GAP_TAU) {            // a split may hide a 4th candidate
        const int s = atomicAdd(nB, 1);
        if (s < CAPB) { listB[s] = n; return; }
    } else {
        int ks[24]; int cnt = 0;
#pragma unroll
        for (int s = 0; s < 8; ++s) {
            if (v0[s] - b1 < GAP_TAU) ks[cnt++] = i0[s];
            if (v1[s] - b1 < GAP_TAU) ks[cnt++] = i1[s];
            if (v2[s] - b1 < GAP_TAU) ks[cnt++] = i2[s];
        }
        if (cnt > 1) {
            const int slot = atomicAdd(nA, 1);
            if (slot < CAPA) {
                int* e = listA + (size_t)slot * 32;
                e[0] = n; e[1] = cnt;
                for (int c = 0; c < cnt; ++c) e[2 + c] = ks[c];
                return;
            }
            const int s2 = atomicAdd(nB, 1);       // overflow safety
            if (s2 < CAPB) { listB[s2] = n; return; }
        }
        // cnt == 1: unique within-TAU candidate = true np argmin
        const int bi = ks[0];
        fidx[n] = bi;
        outIdx[n] = (float)bi;
        atomicAdd(&counts[bi], 1);
        return;
    }
    // listB-overflow fallback (never expected): approx winner
    int bi = 0x7fffffff;
#pragma unroll
    for (int s = 0; s < 8; ++s) if (v0[s] == b1 && i0[s] < bi) bi = i0[s];
    fidx[n] = bi; outIdx[n] = (float)bi; atomicAdd(&counts[bi], 1);
}

// np-exact chain score for each listed candidate; (s,k)-lexicographic min.
// 32 lanes per entry (8 entries per 256-block).
__global__ __launch_bounds__(256)
void exact_kernel(const float* __restrict__ x, const float* __restrict__ emb,
                  const float* __restrict__ ee, const float* __restrict__ xx,
                  const int* __restrict__ listA, const int* __restrict__ nA,
                  int* __restrict__ fidx, float* __restrict__ outIdx,
                  int* __restrict__ counts) {
    int total = *nA; if (total > CAPA) total = CAPA;
    const int sub = threadIdx.x >> 5;
    const int li  = threadIdx.x & 31;
    for (int e = blockIdx.x * 8 + sub; e < total; e += gridDim.x * 8) {
        const int* ent = listA + (size_t)e * 32;
        const int n = ent[0], cnt = ent[1];
        float s = 3.4e38f; int k = 0x7fffffff;
        if (li < cnt) {
            k = ent[2 + li];
            const int b = n >> 10, p = n & 1023;
            const float* xr = x + (size_t)b * 262144 + p;
            const float* er = emb + (size_t)k * 256;
            float dot = 0.f;
#pragma unroll 8
            for (int d = 0; d < 256; ++d)
                dot = __fmaf_rn(er[d], xr[(size_t)d * 1024], dot);
            s = __fmaf_rn(-2.0f, dot, __fadd_rn(xx[n], ee[k]));
        }
#pragma unroll
        for (int off = 1; off < 32; off <<= 1) {
            const float ov = __shfl_xor(s, off, 32);
            const int   ok = __shfl_xor(k, off, 32);
            if (ov < s || (ov == s && ok < k)) { s = ov; k = ok; }
        }
        if (li == 0) { fidx[n] = k; outIdx[n] = (float)k; atomicAdd(&counts[k], 1); }
    }
}

// np-exact full rescan over all 1024 codes for listB rows (safety net, ~0).
__global__ __launch_bounds__(256)
void rescanB_kernel(const float* __restrict__ x, const float* __restrict__ emb,
                    const float* __restrict__ ee, const float* __restrict__ xx,
                    const int* __restrict__ listB, const int* __restrict__ nB,
                    int* __restrict__ fidx, float* __restrict__ outIdx,
                    int* __restrict__ counts) {
    __shared__ float xrow[256];
    __shared__ float bV[4];
    __shared__ int   bI[4];
    int total = *nB; if (total > CAPB) total = CAPB;
    for (int wq = blockIdx.x; wq < total; wq += gridDim.x) {
        const int n = listB[wq];
        const int b = n >> 10, p = n & 1023;
        const float* xb = x + (size_t)b * 262144 + p;
        xrow[threadIdx.x] = xb[(size_t)threadIdx.x * 1024];
        __syncthreads();
        const float xxn = xx[n];
        float best = 3.4e38f; int bi = 0x7fffffff;
        for (int k = threadIdx.x; k < 1024; k += 256) {   // ascending k per thread
            const float* e = emb + (size_t)k * 256;
            float dot = 0.f;
            for (int d = 0; d < 256; ++d) dot = __fmaf_rn(e[d], xrow[d], dot);
            const float t1 = __fadd_rn(xxn, ee[k]);
            const float s = __fmaf_rn(-2.0f, dot, t1);
            if (s < best) { best = s; bi = k; }
        }
        for (int off = 32; off > 0; off >>= 1) {
            const float ov = __shfl_down(best, off, 64);
            const int   oi = __shfl_down(bi,   off, 64);
            if (ov < best || (ov == best && oi < bi)) { best = ov; bi = oi; }
        }
        const int lane = threadIdx.x & 63, wv = threadIdx.x >> 6;
        if (lane == 0) { bV[wv] = best; bI[wv] = bi; }
        __syncthreads();
        if (threadIdx.x == 0) {
            float bb = bV[0]; int ii = bI[0];
            for (int i = 1; i < 4; ++i)
                if (bV[i] < bb || (bV[i] == bb && bI[i] < ii)) { bb = bV[i]; ii = bI[i]; }
            fidx[n] = ii;
            outIdx[n] = (float)ii;
            atomicAdd(&counts[ii], 1);
        }
        __syncthreads();
    }
}

// Quantize: one thread = one pixel x 64 consecutive d. Code row read as
// sequential float4 gathers (each 64B line fetched once); x/out per-d dwords
// coalesced across lanes. tid>>15 = d-chunk, tid&32767 = pixel.
__global__ __launch_bounds__(256)
void quantize_kernel(const float* __restrict__ x, const float* __restrict__ emb,
                     const int* __restrict__ fidx, float* __restrict__ out,
                     float* __restrict__ sumsq) {
    const int tid = blockIdx.x * 256 + threadIdx.x;   // 0..131071
    const int dchunk = tid >> 15;                     // 0..3
    const int n = tid & 32767;
    const int b = n >> 10, p = n & 1023;
    const int d0 = dchunk * 64;
    const int k = fidx[n];
    const float4* er = (const float4*)(emb + (size_t)k * 256 + d0);   // 16 float4
    const float* xr = x + (size_t)b * 262144 + (size_t)d0 * 1024 + p;
    float* orow = out + (size_t)b * 262144 + (size_t)d0 * 1024 + p;
    float loc = 0.f;
#pragma unroll
    for (int j = 0; j < 16; ++j) {
        const float4 qv = er[j];
        const float q[4] = {qv.x, qv.y, qv.z, qv.w};
#pragma unroll
        for (int i = 0; i < 4; ++i) {
            const size_t off = (size_t)(j * 4 + i) * 1024;
            const float xv = xr[off];
            const float e = q[i] - xv;
            orow[off] = xv + e;           // straight-through: x + (q - x)
            loc = fmaf(e, e, loc);
        }
    }
    for (int off = 32; off > 0; off >>= 1) loc += __shfl_down(loc, off, 64);
    __shared__ float red[4];
    const int lane = threadIdx.x & 63, wv = threadIdx.x >> 6;
    if (lane == 0) red[wv] = loc;
    __syncthreads();
    if (threadIdx.x == 0) atomicAdd(sumsq, red[0] + red[1] + red[2] + red[3]);
}

__global__ void finalize_kernel(const int* __restrict__ counts, const float* __restrict__ sumsq,
                                float* __restrict__ outScalars) {
    const int k = threadIdx.x;
    const float p = (float)counts[k] * (1.0f / 32768.0f);
    float term = p * logf(p + 1e-10f);
    for (int off = 32; off > 0; off >>= 1) term += __shfl_down(term, off, 64);
    __shared__ float red[16];
    const int lane = k & 63, wv = k >> 6;
    if (lane == 0) red[wv] = term;
    __syncthreads();
    if (k == 0) {
        float s = 0.f;
        for (int i = 0; i < 16; ++i) s += red[i];
        const float m = sumsq[0] * (1.0f / 8388608.0f);
        outScalars[0] = 1.25f * m;
        outScalars[1] = expf(-s);
    }
}

extern "C" void kernel_launch(void* const* d_in, const int* in_sizes, int n_in,
                              void* d_out, int out_size, void* d_ws, size_t ws_size,
                              hipStream_t stream) {
    const float* x   = (const float*)d_in[0];
    const float* emb = (const float*)d_in[1];
    float* out = (float*)d_out;
    float* W   = (float*)d_ws;
    float* sumsq = W;
    int*   nA    = (int*)(W + 1);
    int*   nB    = (int*)(W + 2);
    int*   counts = (int*)(W + 64);
    float* ee    = W + 1088;
    float* xx    = W + 2112;
    float* pv0   = W + 34880;
    float* pv1   = W + 297024;
    float* pv2   = W + 559168;
    float* pv3   = W + 821312;
    int*   pi0   = (int*)(W + 1083456);
    int*   pi1   = (int*)(W + 1345600);
    int*   pi2   = (int*)(W + 1607744);
    int*   listA = (int*)(W + 1869888);
    int*   listB = (int*)(W + 2394176);
    unsigned short* EhW = (unsigned short*)(W + 2402368);
    unsigned short* ElW = (unsigned short*)(W + 2533440);
    int*   fidx  = (int*)(W + 2664512);

    hipMemsetAsync(W, 0, 1088 * sizeof(float), stream);  // sumsq + nA/nB + counts
    prep_kernel<<<388, 256, 0, stream>>>(emb, x, ee, xx, EhW, ElW);
    mfma_argmin_kernel<<<2048, 256, 0, stream>>>(x, EhW, ElW, ee, xx,
                                                 pv0, pv1, pv2, pv3, pi0, pi1, pi2);
    combine_kernel<<<128, 256, 0, stream>>>(pv0, pv1, pv2, pv3, pi0, pi1, pi2,
                                            fidx, out + 8388610, counts, listA, nA, listB, nB);
    exact_kernel<<<512, 256, 0, stream>>>(x, emb, ee, xx, listA, nA, fidx, out + 8388610, counts);
    rescanB_kernel<<<64, 256, 0, stream>>>(x, emb, ee, xx, listB, nB, fidx, out + 8388610, counts);
    quantize_kernel<<<512, 256, 0, stream>>>(x, emb, fidx, out, sumsq);
    finalize_kernel<<<1, 1024, 0, stream>>>(counts, sumsq, out + 8388608);
}